// Round 1
// baseline (12334.229 us; speedup 1.0000x reference)
//
#include <hip/hip_runtime.h>
#include <math.h>

namespace {

constexpr int NL = 2, NH = 8, DH = 256;
constexpr int NB = 2, SEQP = 1024, SEQS = 256, SEQ = SEQP + SEQS;
constexpr int DIMP = 2048, DIME = 1024, FFP = 8192, FFE = 4096;
constexpr int HH = NH * DH;  // 2048

// ---------------- elementwise / small kernels ----------------

__global__ void copy4_k(float4* __restrict__ dst, const float4* __restrict__ src) {
  long i = (long)blockIdx.x * blockDim.x + threadIdx.x;
  dst[i] = src[i];
}

__global__ void rope_tab_k(const int* __restrict__ pos, float* __restrict__ cosb,
                           float* __restrict__ sinb) {
  long bs = blockIdx.x;  // b*SEQ + s
  int d = threadIdx.x;   // 0..DH-1
  int i = d & (DH / 2 - 1);
  float inv = expf(-(2.0f * (float)i / (float)DH) * logf(10000.0f));
  float ang = (float)pos[bs] * inv;
  cosb[bs * DH + d] = cosf(ang);
  sinb[bs * DH + d] = sinf(ang);
}

// partial cond @ W over d-chunks: part[(chunk*2+b)*twoD + j]
__global__ __launch_bounds__(256) void ada_k(const float* __restrict__ cond,
    const float* __restrict__ W, float* __restrict__ part, int D, int twoD) {
  __shared__ float lc[2 * 2048];
  int t = threadIdx.x;
  int j = blockIdx.x * 256 + t;
  int nch = gridDim.y;
  int chunk = blockIdx.y;
  int cl = D / nch;
  int d0 = chunk * cl;
  for (int i = t; i < 2 * D; i += 256) lc[i] = cond[i];
  __syncthreads();
  float a0 = 0.f, a1 = 0.f;
  for (int d = d0; d < d0 + cl; ++d) {
    float wvv = W[(long)d * twoD + j];
    a0 = fmaf(lc[d], wvv, a0);
    a1 = fmaf(lc[D + d], wvv, a1);
  }
  part[((long)chunk * 2 + 0) * twoD + j] = a0;
  part[((long)chunk * 2 + 1) * twoD + j] = a1;
}

__global__ void ada_red_k(const float* __restrict__ part, float* __restrict__ sg,
                          int twoD, int nch) {
  int idx = blockIdx.x * 256 + threadIdx.x;  // over [2][twoD]
  int b = idx / twoD, j = idx - b * twoD;
  float s = 0.f;
  for (int c = 0; c < nch; ++c) s += part[((long)c * 2 + b) * twoD + j];
  sg[(long)b * twoD + j] = s;
}

// out[row] = rms(x[row]) * (1 + scale[b]); sg layout [B][2D] (scale | gate)
__global__ __launch_bounds__(256) void rms_k(const float* __restrict__ x,
    const float* __restrict__ sg, float* __restrict__ out, int D, int rowsPerB) {
  long row = blockIdx.x;
  int b = (int)(row / rowsPerB);
  const float* xr = x + row * (long)D;
  float* po = out + row * (long)D;
  const float* sc = sg + (long)b * 2 * D;
  int t = threadIdx.x;
  float ss = 0.f;
  for (int i = t; i < D; i += 256) { float v = xr[i]; ss = fmaf(v, v, ss); }
  for (int o = 32; o; o >>= 1) ss += __shfl_xor(ss, o);
  __shared__ float wr[4];
  if ((t & 63) == 0) wr[t >> 6] = ss;
  __syncthreads();
  float rs = rsqrtf((wr[0] + wr[1] + wr[2] + wr[3]) / (float)D + 1e-6f);
  for (int i = t; i < D; i += 256) po[i] = xr[i] * rs * (1.f + sc[i]);
}

// x += y * gate ; g points at the gate half (sg + D), indexed g[b*2D + d]
__global__ void gated_add_k(float* __restrict__ x, const float* __restrict__ y,
                            const float* __restrict__ g, int D, int rowsPerB) {
  long idx = (long)blockIdx.x * 256 + threadIdx.x;
  int d = (int)(idx % D);
  int b = (int)(idx / ((long)rowsPerB * D));
  x[idx] = fmaf(y[idx], g[(long)b * 2 * D + d], x[idx]);
}

// qt/kt/vt: [B*Si, HH]; write joint [B,NH,SEQ,DH] with RoPE on q,k
__global__ __launch_bounds__(256) void rope_scatter_k(const float* __restrict__ qt,
    const float* __restrict__ kt, const float* __restrict__ vt,
    const float* __restrict__ cosb, const float* __restrict__ sinb,
    float* __restrict__ qj, float* __restrict__ kj, float* __restrict__ vj,
    int Si, int ofs) {
  long bs = blockIdx.x;
  int b = (int)(bs / Si), s = (int)(bs % Si);
  int c = blockIdx.y * 256 + threadIdx.x;  // 0..HH-1
  int h = c >> 8, hd = c & 255;
  long tin = bs * (long)HH;
  float q = qt[tin + c], k = kt[tin + c], v = vt[tin + c];
  float qp = qt[tin + (c ^ 128)], kp = kt[tin + (c ^ 128)];
  long sgi = ((long)b * SEQ + ofs + s) * DH + hd;
  float cv = cosb[sgi], sv = sinb[sgi];
  float qr = (hd < 128) ? -qp : qp;
  float kr = (hd < 128) ? -kp : kp;
  long oidx = (((long)b * NH + h) * SEQ + ofs + s) * (long)DH + hd;
  qj[oidx] = fmaf(q, cv, qr * sv);
  kj[oidx] = fmaf(k, cv, kr * sv);
  vj[oidx] = v;
}

// row softmax of scores[z][q][:] with 1/sqrt(DH) scaling; mask is all-true -> bias 0
__global__ __launch_bounds__(256) void softmax_k(float* __restrict__ scores) {
  float* p = scores + (long)blockIdx.y * SEQ * SEQ + (long)blockIdx.x * SEQ;
  int t = threadIdx.x;
  float v[5];
  float mx = -3.4e38f;
#pragma unroll
  for (int i = 0; i < 5; ++i) { v[i] = p[t + i * 256] * 0.0625f; mx = fmaxf(mx, v[i]); }
  for (int o = 32; o; o >>= 1) mx = fmaxf(mx, __shfl_xor(mx, o));
  __shared__ float wr[4];
  if ((t & 63) == 0) wr[t >> 6] = mx;
  __syncthreads();
  mx = fmaxf(fmaxf(wr[0], wr[1]), fmaxf(wr[2], wr[3]));
  __syncthreads();
  float s = 0.f;
#pragma unroll
  for (int i = 0; i < 5; ++i) { v[i] = expf(v[i] - mx); s += v[i]; }
  for (int o = 32; o; o >>= 1) s += __shfl_xor(s, o);
  if ((t & 63) == 0) wr[t >> 6] = s;
  __syncthreads();
  float inv = 1.f / (wr[0] + wr[1] + wr[2] + wr[3]);
#pragma unroll
  for (int i = 0; i < 5; ++i) p[t + i * 256] = v[i] * inv;
}

// ---------------- tiled fp32 GEMM ----------------
// C[M,N] = A[M,K] @ op(B); BT=1 -> B is [N,K] row-major (C = A B^T).
// 128x128x16 tile, 256 threads, 8x8 micro-tile.
// Batch: z = blockIdx.z; z1=z/bdiv, z2=z%bdiv; X += z1*sX1 + z2*sX2.
// EPI: 0 = store, 1 = store tanh-gelu(acc), 2 = C *= acc.
template <int EPI, int BT>
__global__ __launch_bounds__(256) void gemm_k(const float* __restrict__ A,
    const float* __restrict__ Bm, float* __restrict__ C, int K,
    int lda, int ldb, int ldc,
    long sA1, long sA2, long sB1, long sB2, long sC1, long sC2, int bdiv) {
  __shared__ float As[16][128];
  __shared__ float Bs[16][128];
  int t = threadIdx.x;
  int z = blockIdx.z, z1 = z / bdiv, z2 = z % bdiv;
  A += z1 * sA1 + z2 * sA2;
  Bm += z1 * sB1 + z2 * sB2;
  C += z1 * sC1 + z2 * sC2;
  int m0 = blockIdx.y * 128, n0 = blockIdx.x * 128;
  int ar = t >> 2, ac = (t & 3) << 2;   // A (and B^T) loader
  int br = t >> 5, bc = (t & 31) << 2;  // B (NN) loader
  int tx = t & 15, ty = t >> 4;
  float acc[8][8] = {};
  for (int k0 = 0; k0 < K; k0 += 16) {
    float4 av0 = *(const float4*)(A + (long)(m0 + ar) * lda + k0 + ac);
    float4 av1 = *(const float4*)(A + (long)(m0 + ar + 64) * lda + k0 + ac);
    float4 bv0, bv1;
    if (BT) {
      bv0 = *(const float4*)(Bm + (long)(n0 + ar) * ldb + k0 + ac);
      bv1 = *(const float4*)(Bm + (long)(n0 + ar + 64) * ldb + k0 + ac);
    } else {
      bv0 = *(const float4*)(Bm + (long)(k0 + br) * ldb + n0 + bc);
      bv1 = *(const float4*)(Bm + (long)(k0 + br + 8) * ldb + n0 + bc);
    }
    __syncthreads();
    As[ac + 0][ar] = av0.x; As[ac + 1][ar] = av0.y;
    As[ac + 2][ar] = av0.z; As[ac + 3][ar] = av0.w;
    As[ac + 0][ar + 64] = av1.x; As[ac + 1][ar + 64] = av1.y;
    As[ac + 2][ar + 64] = av1.z; As[ac + 3][ar + 64] = av1.w;
    if (BT) {
      Bs[ac + 0][ar] = bv0.x; Bs[ac + 1][ar] = bv0.y;
      Bs[ac + 2][ar] = bv0.z; Bs[ac + 3][ar] = bv0.w;
      Bs[ac + 0][ar + 64] = bv1.x; Bs[ac + 1][ar + 64] = bv1.y;
      Bs[ac + 2][ar + 64] = bv1.z; Bs[ac + 3][ar + 64] = bv1.w;
    } else {
      *(float4*)&Bs[br][bc] = bv0;
      *(float4*)&Bs[br + 8][bc] = bv1;
    }
    __syncthreads();
#pragma unroll
    for (int kk = 0; kk < 16; ++kk) {
      float4 a0 = *(const float4*)&As[kk][ty << 3];
      float4 a1 = *(const float4*)&As[kk][(ty << 3) + 4];
      float4 b0 = *(const float4*)&Bs[kk][tx << 3];
      float4 b1 = *(const float4*)&Bs[kk][(tx << 3) + 4];
      float a[8] = {a0.x, a0.y, a0.z, a0.w, a1.x, a1.y, a1.z, a1.w};
      float b[8] = {b0.x, b0.y, b0.z, b0.w, b1.x, b1.y, b1.z, b1.w};
#pragma unroll
      for (int i = 0; i < 8; ++i)
#pragma unroll
        for (int j = 0; j < 8; ++j) acc[i][j] = fmaf(a[i], b[j], acc[i][j]);
    }
  }
#pragma unroll
  for (int i = 0; i < 8; ++i) {
#pragma unroll
    for (int j = 0; j < 8; ++j) {
      long idx = (long)(m0 + (ty << 3) + i) * ldc + n0 + (tx << 3) + j;
      float v = acc[i][j];
      if (EPI == 0) C[idx] = v;
      else if (EPI == 1)
        C[idx] = 0.5f * v * (1.f + tanhf(0.7978845608028654f * fmaf(0.044715f * v, v * v, v)));
      else C[idx] *= v;
    }
  }
}

}  // namespace

extern "C" void kernel_launch(void* const* d_in, const int* in_sizes, int n_in,
                              void* d_out, int out_size, void* d_ws, size_t ws_size,
                              hipStream_t stream) {
  (void)in_sizes; (void)n_in; (void)out_size;
  const float* emb_p = (const float*)d_in[0];
  const float* emb_e = (const float*)d_in[1];
  const float* cond[2] = {(const float*)d_in[2], (const float*)d_in[3]};
  const float* ada1[2] = {(const float*)d_in[4], (const float*)d_in[14]};
  const float* ada2[2] = {(const float*)d_in[5], (const float*)d_in[15]};
  const float* adaF[2] = {(const float*)d_in[6], (const float*)d_in[16]};
  const float* wq[2] = {(const float*)d_in[7], (const float*)d_in[17]};
  const float* wk[2] = {(const float*)d_in[8], (const float*)d_in[18]};
  const float* wv[2] = {(const float*)d_in[9], (const float*)d_in[19]};
  const float* wo[2] = {(const float*)d_in[10], (const float*)d_in[20]};
  const float* wg[2] = {(const float*)d_in[11], (const float*)d_in[21]};
  const float* wu[2] = {(const float*)d_in[12], (const float*)d_in[22]};
  const float* wd[2] = {(const float*)d_in[13], (const float*)d_in[23]};
  const int* pos = (const int*)d_in[24];
  // d_in[25] attn_mask: all-true in this problem -> bias = 0, ignored.

  const int Ds[2] = {DIMP, DIME};
  const int Fs[2] = {FFP, FFE};
  const int Sis[2] = {SEQP, SEQS};
  const int ofss[2] = {0, SEQP};

  float* w = (float*)d_ws;
  size_t off = 0;
  auto alloc = [&](size_t n) { float* r = w + off; off += n; return r; };
  float* xs[2]; float* hb[2]; float* sg[2];
  xs[0] = alloc((size_t)NB * SEQP * DIMP);
  xs[1] = alloc((size_t)NB * SEQS * DIME);
  float* cosb = alloc((size_t)NB * SEQ * DH);
  float* sinb = alloc((size_t)NB * SEQ * DH);
  sg[0] = alloc((size_t)NB * 2 * DIMP);
  sg[1] = alloc((size_t)NB * 2 * DIME);
  float* part = alloc((size_t)8 * 2 * 2 * DIMP);
  hb[0] = alloc((size_t)NB * SEQP * DIMP);
  hb[1] = alloc((size_t)NB * SEQS * DIME);
  float* qt = alloc((size_t)NB * SEQP * HH);
  float* kt = alloc((size_t)NB * SEQP * HH);
  float* vt = alloc((size_t)NB * SEQP * HH);
  float* qj = alloc((size_t)NB * NH * SEQ * DH);
  float* kj = alloc((size_t)NB * NH * SEQ * DH);
  float* vj = alloc((size_t)NB * NH * SEQ * DH);
  float* att2 = alloc((size_t)NB * SEQ * HH);
  float* tmp = alloc((size_t)NB * SEQP * DIMP);
  float* scores = alloc((size_t)NB * NH * SEQ * SEQ);
  float* ff = scores;  // reuse: attention scratch and MLP intermediate never coexist
  if (off * sizeof(float) > ws_size) return;  // fail loudly (output stays poisoned)

  // residual streams = embeddings
  copy4_k<<<(NB * SEQP * DIMP / 4) / 256, 256, 0, stream>>>((float4*)xs[0], (const float4*)emb_p);
  copy4_k<<<(NB * SEQS * DIME / 4) / 256, 256, 0, stream>>>((float4*)xs[1], (const float4*)emb_e);
  rope_tab_k<<<NB * SEQ, DH, 0, stream>>>(pos, cosb, sinb);

  for (int l = 0; l < NL; ++l) {
    for (int i = 0; i < 2; ++i) {
      int D = Ds[i], Si = Sis[i];
      const float* a1 = ada1[i] + (size_t)l * D * 2 * D;
      ada_k<<<dim3(2 * D / 256, 8), 256, 0, stream>>>(cond[i], a1, part, D, 2 * D);
      ada_red_k<<<4 * D / 256, 256, 0, stream>>>(part, sg[i], 2 * D, 8);
      rms_k<<<NB * Si, 256, 0, stream>>>(xs[i], sg[i], hb[i], D, Si);
      dim3 gq(HH / 128, NB * Si / 128, 1);
      const float* wql = wq[i] + (size_t)l * D * HH;
      const float* wkl = wk[i] + (size_t)l * D * HH;
      const float* wvl = wv[i] + (size_t)l * D * HH;
      gemm_k<0, 0><<<gq, 256, 0, stream>>>(hb[i], wql, qt, D, D, HH, HH, 0, 0, 0, 0, 0, 0, 1);
      gemm_k<0, 0><<<gq, 256, 0, stream>>>(hb[i], wkl, kt, D, D, HH, HH, 0, 0, 0, 0, 0, 0, 1);
      gemm_k<0, 0><<<gq, 256, 0, stream>>>(hb[i], wvl, vt, D, D, HH, HH, 0, 0, 0, 0, 0, 0, 1);
      rope_scatter_k<<<dim3(NB * Si, HH / 256), 256, 0, stream>>>(qt, kt, vt, cosb, sinb,
                                                                  qj, kj, vj, Si, ofss[i]);
    }
    // joint attention: scores = q k^T / sqrt(DH); softmax; att2[b,s,h*DH+hd] = P v
    gemm_k<0, 1><<<dim3(SEQ / 128, SEQ / 128, NB * NH), 256, 0, stream>>>(
        qj, kj, scores, DH, DH, DH, SEQ,
        (long)SEQ * DH, 0, (long)SEQ * DH, 0, (long)SEQ * SEQ, 0, 1);
    softmax_k<<<dim3(SEQ, NB * NH), 256, 0, stream>>>(scores);
    gemm_k<0, 0><<<dim3(DH / 128, SEQ / 128, NB * NH), 256, 0, stream>>>(
        scores, vj, att2, SEQ, SEQ, DH, HH,
        (long)NH * SEQ * SEQ, (long)SEQ * SEQ,
        (long)NH * SEQ * DH, (long)SEQ * DH,
        (long)SEQ * HH, (long)DH, NH);
    for (int i = 0; i < 2; ++i) {
      int D = Ds[i], F = Fs[i], Si = Sis[i];
      const float* wol = wo[i] + (size_t)l * HH * D;
      gemm_k<0, 0><<<dim3(D / 128, Si / 128, NB), 256, 0, stream>>>(
          att2 + (long)ofss[i] * HH, wol, tmp, HH, HH, D, D,
          (long)SEQ * HH, 0, 0, 0, (long)Si * D, 0, 1);
      gated_add_k<<<NB * Si * D / 256, 256, 0, stream>>>(xs[i], tmp, sg[i] + D, D, Si);
      const float* a2 = ada2[i] + (size_t)l * D * 2 * D;
      ada_k<<<dim3(2 * D / 256, 8), 256, 0, stream>>>(cond[i], a2, part, D, 2 * D);
      ada_red_k<<<4 * D / 256, 256, 0, stream>>>(part, sg[i], 2 * D, 8);
      rms_k<<<NB * Si, 256, 0, stream>>>(xs[i], sg[i], hb[i], D, Si);
      const float* wgl = wg[i] + (size_t)l * D * F;
      const float* wul = wu[i] + (size_t)l * D * F;
      const float* wdl = wd[i] + (size_t)l * F * D;
      dim3 gf(F / 128, NB * Si / 128, 1);
      gemm_k<1, 0><<<gf, 256, 0, stream>>>(hb[i], wgl, ff, D, D, F, F, 0, 0, 0, 0, 0, 0, 1);
      gemm_k<2, 0><<<gf, 256, 0, stream>>>(hb[i], wul, ff, D, D, F, F, 0, 0, 0, 0, 0, 0, 1);
      gemm_k<0, 0><<<dim3(D / 128, NB * Si / 128, 1), 256, 0, stream>>>(
          ff, wdl, tmp, F, F, D, D, 0, 0, 0, 0, 0, 0, 1);
      gated_add_k<<<NB * Si * D / 256, 256, 0, stream>>>(xs[i], tmp, sg[i] + D, D, Si);
    }
  }
  // final AdaRMS (gate unused)
  float* outp = (float*)d_out;
  for (int i = 0; i < 2; ++i) {
    int D = Ds[i], Si = Sis[i];
    ada_k<<<dim3(2 * D / 256, 8), 256, 0, stream>>>(cond[i], adaF[i], part, D, 2 * D);
    ada_red_k<<<4 * D / 256, 256, 0, stream>>>(part, sg[i], 2 * D, 8);
    rms_k<<<NB * Si, 256, 0, stream>>>(xs[i], sg[i], outp, D, Si);
    outp += (size_t)NB * Si * D;
  }
}

// Round 2
// 2975.731 us; speedup vs baseline: 4.1449x; 4.1449x over previous
//
#include <hip/hip_runtime.h>
#include <math.h>

namespace {

constexpr int NL = 2, NH = 8, DH = 256;
constexpr int NB = 2, SEQP = 1024, SEQS = 256, SEQ = SEQP + SEQS;
constexpr int DIMP = 2048, DIME = 1024, FFP = 8192, FFE = 4096;
constexpr int HH = NH * DH;  // 2048

typedef __attribute__((ext_vector_type(8))) short bf16x8;
typedef __attribute__((ext_vector_type(4))) float f32x4;

__device__ inline ushort f2b(float f) {
  union { float f; unsigned u; } x{f};
  unsigned r = (x.u + 0x7FFFu + ((x.u >> 16) & 1u)) >> 16;
  return (ushort)r;
}
__device__ inline float b2f(ushort u) {
  union { unsigned u; float f; } x{(unsigned)u << 16};
  return x.f;
}
__device__ inline void stv(float* p, float v) { *p = v; }
__device__ inline void stv(ushort* p, float v) { *p = f2b(v); }

__device__ inline void gld16(const void* g, void* l) {
  __builtin_amdgcn_global_load_lds(
      (const __attribute__((address_space(1))) void*)g,
      (__attribute__((address_space(3))) void*)l, 16, 0, 0);
}

// ---------------- elementwise / small kernels ----------------

__global__ void copy4_k(float4* __restrict__ dst, const float4* __restrict__ src) {
  long i = (long)blockIdx.x * blockDim.x + threadIdx.x;
  dst[i] = src[i];
}

__global__ void rope_tab_k(const int* __restrict__ pos, float* __restrict__ cosb,
                           float* __restrict__ sinb) {
  long bs = blockIdx.x;
  int d = threadIdx.x;
  int i = d & (DH / 2 - 1);
  float inv = expf(-(2.0f * (float)i / (float)DH) * logf(10000.0f));
  float ang = (float)pos[bs] * inv;
  cosb[bs * DH + d] = cosf(ang);
  sinb[bs * DH + d] = sinf(ang);
}

__global__ __launch_bounds__(256) void ada_k(const float* __restrict__ cond,
    const float* __restrict__ W, float* __restrict__ part, int D, int twoD) {
  __shared__ float lc[2 * 2048];
  int t = threadIdx.x;
  int j = blockIdx.x * 256 + t;
  int chunk = blockIdx.y;
  int cl = D / gridDim.y;
  int d0 = chunk * cl;
  for (int i = t; i < 2 * D; i += 256) lc[i] = cond[i];
  __syncthreads();
  float a0 = 0.f, a1 = 0.f;
  for (int d = d0; d < d0 + cl; ++d) {
    float wvv = W[(long)d * twoD + j];
    a0 = fmaf(lc[d], wvv, a0);
    a1 = fmaf(lc[D + d], wvv, a1);
  }
  part[((long)chunk * 2 + 0) * twoD + j] = a0;
  part[((long)chunk * 2 + 1) * twoD + j] = a1;
}

__global__ void ada_red_k(const float* __restrict__ part, float* __restrict__ sg,
                          int twoD, int nch) {
  int idx = blockIdx.x * 256 + threadIdx.x;
  int b = idx / twoD, j = idx - b * twoD;
  float s = 0.f;
  for (int c = 0; c < nch; ++c) s += part[((long)c * 2 + b) * twoD + j];
  sg[(long)b * twoD + j] = s;
}

template <typename OT>
__global__ __launch_bounds__(256) void rms_k(const float* __restrict__ x,
    const float* __restrict__ sg, OT* __restrict__ out, int D, int rowsPerB) {
  long row = blockIdx.x;
  int b = (int)(row / rowsPerB);
  const float* xr = x + row * (long)D;
  OT* po = out + row * (long)D;
  const float* sc = sg + (long)b * 2 * D;
  int t = threadIdx.x;
  float ss = 0.f;
  for (int i = t; i < D; i += 256) { float v = xr[i]; ss = fmaf(v, v, ss); }
  for (int o = 32; o; o >>= 1) ss += __shfl_xor(ss, o);
  __shared__ float wr[4];
  if ((t & 63) == 0) wr[t >> 6] = ss;
  __syncthreads();
  float rs = rsqrtf((wr[0] + wr[1] + wr[2] + wr[3]) / (float)D + 1e-6f);
  for (int i = t; i < D; i += 256) stv(po + i, xr[i] * rs * (1.f + sc[i]));
}

__global__ void gated_add_k(float* __restrict__ x, const float* __restrict__ y,
                            const float* __restrict__ g, int D, int rowsPerB) {
  long idx = (long)blockIdx.x * 256 + threadIdx.x;
  int d = (int)(idx % D);
  int b = (int)(idx / ((long)rowsPerB * D));
  x[idx] = fmaf(y[idx], g[(long)b * 2 * D + d], x[idx]);
}

// fp32 [K][N] -> bf16 [N][K] transpose-convert
__global__ __launch_bounds__(256) void wconv_k(const float* __restrict__ in,
    ushort* __restrict__ out, int N, int K) {
  __shared__ float tile[64][65];
  int n0 = blockIdx.x << 6, k0 = blockIdx.y << 6;
  int t = threadIdx.x, r = t >> 4, c4 = (t & 15) << 2;
#pragma unroll
  for (int rr = 0; rr < 64; rr += 16) {
    float4 v = *(const float4*)(in + (long)(k0 + r + rr) * N + n0 + c4);
    tile[r + rr][c4 + 0] = v.x; tile[r + rr][c4 + 1] = v.y;
    tile[r + rr][c4 + 2] = v.z; tile[r + rr][c4 + 3] = v.w;
  }
  __syncthreads();
#pragma unroll
  for (int rr = 0; rr < 64; rr += 16) {
    int n = r + rr;
    ushort4 o;
    o.x = f2b(tile[c4 + 0][n]); o.y = f2b(tile[c4 + 1][n]);
    o.z = f2b(tile[c4 + 2][n]); o.w = f2b(tile[c4 + 3][n]);
    *(ushort4*)(out + (long)(n0 + n) * K + k0 + c4) = o;
  }
}

// qt/kt bf16 [B*Si][HH] -> RoPE -> qj/kj bf16 [B,NH,SEQ,DH]
__global__ __launch_bounds__(256) void rope_qk_k(const ushort* __restrict__ qt,
    const ushort* __restrict__ kt, const float* __restrict__ cosb,
    const float* __restrict__ sinb, ushort* __restrict__ qj, ushort* __restrict__ kj,
    int Si, int ofs) {
  long bs = blockIdx.x;
  int b = (int)(bs / Si), s = (int)(bs % Si);
  int c = blockIdx.y * 256 + threadIdx.x;
  int h = c >> 8, hd = c & 255;
  long tin = bs * (long)HH;
  float q = b2f(qt[tin + c]), k = b2f(kt[tin + c]);
  float qp = b2f(qt[tin + (c ^ 128)]), kp = b2f(kt[tin + (c ^ 128)]);
  long sgi = ((long)b * SEQ + ofs + s) * DH + hd;
  float cv = cosb[sgi], sv = sinb[sgi];
  float qr = (hd < 128) ? -qp : qp, kr = (hd < 128) ? -kp : kp;
  long o = (((long)b * NH + h) * SEQ + ofs + s) * (long)DH + hd;
  qj[o] = f2b(fmaf(q, cv, qr * sv));
  kj[o] = f2b(fmaf(k, cv, kr * sv));
}

// vt bf16 [B*Si][HH] -> vjT bf16 [B,NH,DH,SEQ]
__global__ __launch_bounds__(256) void vtrans_k(const ushort* __restrict__ vt,
    ushort* __restrict__ vjT, int Si, int ofs) {
  __shared__ ushort tile[64][80];
  int z = blockIdx.z, b = z >> 3, h = z & 7;
  int s0 = blockIdx.x << 6, d0 = blockIdx.y << 6;
  int t = threadIdx.x, r = t >> 3, c8 = (t & 7) << 3;
#pragma unroll
  for (int rr = 0; rr < 64; rr += 32) {
    const ushort* src = vt + ((long)(b * Si + s0 + r + rr)) * HH + h * DH + d0 + c8;
    *(uint4*)&tile[r + rr][c8] = *(const uint4*)src;
  }
  __syncthreads();
#pragma unroll
  for (int rr = 0; rr < 64; rr += 32) {
    int drow = r + rr;
    ushort o[8];
#pragma unroll
    for (int j = 0; j < 8; ++j) o[j] = tile[c8 + j][drow];
    *(uint4*)(vjT + ((long)(b * NH + h) * DH + d0 + drow) * SEQ + ofs + s0 + c8) =
        *(const uint4*)o;
  }
}

// softmax over fp32 scores row; writes bf16 probs in place (first half of row)
__global__ __launch_bounds__(256) void softmax_k(float* __restrict__ scores) {
  float* p = scores + (long)blockIdx.y * SEQ * SEQ + (long)blockIdx.x * SEQ;
  ushort* po = (ushort*)p;
  int t = threadIdx.x;
  float v[5];
  float mx = -3.4e38f;
#pragma unroll
  for (int i = 0; i < 5; ++i) { v[i] = p[t + i * 256] * 0.0625f; mx = fmaxf(mx, v[i]); }
  for (int o = 32; o; o >>= 1) mx = fmaxf(mx, __shfl_xor(mx, o));
  __shared__ float wr[4];
  if ((t & 63) == 0) wr[t >> 6] = mx;
  __syncthreads();
  mx = fmaxf(fmaxf(wr[0], wr[1]), fmaxf(wr[2], wr[3]));
  __syncthreads();
  float s = 0.f;
#pragma unroll
  for (int i = 0; i < 5; ++i) { v[i] = expf(v[i] - mx); s += v[i]; }
  for (int o = 32; o; o >>= 1) s += __shfl_xor(s, o);
  if ((t & 63) == 0) wr[t >> 6] = s;
  __syncthreads();
  float inv = 1.f / (wr[0] + wr[1] + wr[2] + wr[3]);
#pragma unroll
  for (int i = 0; i < 5; ++i) po[t + i * 256] = f2b(v[i] * inv);
}

// ---------------- bf16 MFMA GEMM (m97 structure) ----------------
// C[M,N] = A[M,K] (bf16, row-major) @ B^T where B is [N][K] bf16 row-major.
// 128x128 tile, BK=32, 256 threads = 4 waves (2x2), 4x4 16x16x32 frags/wave.
// Batch: z1 = z/bdiv, z2 = z%bdiv; strides in elements of respective buffer.
// EPI: 0 = f32 store to Cf; 1 = bf16 store to Cb; 2 = Cb = bf16(gelu(Cf)*acc).
template <int EPI>
__global__ __launch_bounds__(256) void bgemm_k(
    const ushort* __restrict__ A, const ushort* __restrict__ B,
    float* __restrict__ Cf, ushort* __restrict__ Cb, int K,
    int lda, int ldb, int ldc,
    long sA1, long sA2, long sB1, long sB2, long sC1, long sC2, int bdiv) {
  __shared__ ushort As[128 * 32];
  __shared__ ushort Bs[128 * 32];
  int t = threadIdx.x;
  int z = blockIdx.z, z1 = z / bdiv, z2 = z % bdiv;
  A += z1 * sA1 + z2 * sA2;
  B += z1 * sB1 + z2 * sB2;
  long cofs = z1 * sC1 + z2 * sC2;
  int m0 = blockIdx.y * 128, n0 = blockIdx.x * 128;
  int srow = t >> 2, scol = (t & 3) << 3;  // 16B per thread
  const ushort* gA0 = A + (long)(m0 + srow) * lda + scol;
  const ushort* gA1 = A + (long)(m0 + srow + 64) * lda + scol;
  const ushort* gB0 = B + (long)(n0 + srow) * ldb + scol;
  const ushort* gB1 = B + (long)(n0 + srow + 64) * ldb + scol;
  ushort* lA0 = &As[srow * 32 + scol];
  ushort* lA1 = &As[(srow + 64) * 32 + scol];
  ushort* lB0 = &Bs[srow * 32 + scol];
  ushort* lB1 = &Bs[(srow + 64) * 32 + scol];
  int lane = t & 63;
  int wm = ((t >> 6) & 1) << 6, wn = (t >> 7) << 6;
  int fr = lane & 15, fk = (lane >> 4) << 3;
  f32x4 acc[4][4] = {};
  for (int k0 = 0; k0 < K; k0 += 32) {
    if (k0) __syncthreads();
    gld16(gA0 + k0, lA0);
    gld16(gA1 + k0, lA1);
    gld16(gB0 + k0, lB0);
    gld16(gB1 + k0, lB1);
    __syncthreads();
    bf16x8 a[4], b[4];
#pragma unroll
    for (int m = 0; m < 4; ++m)
      a[m] = *(const bf16x8*)&As[(wm + m * 16 + fr) * 32 + fk];
#pragma unroll
    for (int n = 0; n < 4; ++n)
      b[n] = *(const bf16x8*)&Bs[(wn + n * 16 + fr) * 32 + fk];
#pragma unroll
    for (int m = 0; m < 4; ++m)
#pragma unroll
      for (int n = 0; n < 4; ++n)
        acc[m][n] = __builtin_amdgcn_mfma_f32_16x16x32_bf16(a[m], b[n], acc[m][n], 0, 0, 0);
  }
  int cr = (lane >> 4) << 2, cc = lane & 15;
#pragma unroll
  for (int m = 0; m < 4; ++m) {
    int row = m0 + wm + m * 16 + cr;
#pragma unroll
    for (int n = 0; n < 4; ++n) {
      int col = n0 + wn + n * 16 + cc;
#pragma unroll
      for (int r = 0; r < 4; ++r) {
        long idx = cofs + (long)(row + r) * ldc + col;
        float v = acc[m][n][r];
        if (EPI == 0) {
          Cf[idx] = v;
        } else if (EPI == 1) {
          Cb[idx] = f2b(v);
        } else {
          float g = Cf[idx];
          float ge = 0.5f * g * (1.f + tanhf(0.7978845608028654f * fmaf(0.044715f * g, g * g, g)));
          Cb[idx] = f2b(ge * v);
        }
      }
    }
  }
}

}  // namespace

extern "C" void kernel_launch(void* const* d_in, const int* in_sizes, int n_in,
                              void* d_out, int out_size, void* d_ws, size_t ws_size,
                              hipStream_t stream) {
  (void)in_sizes; (void)n_in; (void)out_size;
  const float* emb_p = (const float*)d_in[0];
  const float* emb_e = (const float*)d_in[1];
  const float* cond[2] = {(const float*)d_in[2], (const float*)d_in[3]};
  const float* ada1[2] = {(const float*)d_in[4], (const float*)d_in[14]};
  const float* ada2[2] = {(const float*)d_in[5], (const float*)d_in[15]};
  const float* adaF[2] = {(const float*)d_in[6], (const float*)d_in[16]};
  const float* wq[2] = {(const float*)d_in[7], (const float*)d_in[17]};
  const float* wk[2] = {(const float*)d_in[8], (const float*)d_in[18]};
  const float* wv[2] = {(const float*)d_in[9], (const float*)d_in[19]};
  const float* wo[2] = {(const float*)d_in[10], (const float*)d_in[20]};
  const float* wg[2] = {(const float*)d_in[11], (const float*)d_in[21]};
  const float* wu[2] = {(const float*)d_in[12], (const float*)d_in[22]};
  const float* wd[2] = {(const float*)d_in[13], (const float*)d_in[23]};
  const int* pos = (const int*)d_in[24];

  const int Ds[2] = {DIMP, DIME};
  const int Fs[2] = {FFP, FFE};
  const int Sis[2] = {SEQP, SEQS};
  const int ofss[2] = {0, SEQP};

  char* base = (char*)d_ws;
  size_t off = 0;
  auto alF = [&](size_t n) { float* r = (float*)(base + off); off += (n * 4 + 255) & ~(size_t)255; return r; };
  auto alH = [&](size_t n) { ushort* r = (ushort*)(base + off); off += (n * 2 + 255) & ~(size_t)255; return r; };

  float* xs[2]; ushort* hb[2]; float* sg[2];
  xs[0] = alF((size_t)NB * SEQP * DIMP);
  xs[1] = alF((size_t)NB * SEQS * DIME);
  float* cosb = alF((size_t)NB * SEQ * DH);
  float* sinb = alF((size_t)NB * SEQ * DH);
  sg[0] = alF((size_t)NB * 2 * DIMP);
  sg[1] = alF((size_t)NB * 2 * DIME);
  float* part = alF((size_t)8 * 2 * 2 * DIMP);
  float* tmp = alF((size_t)NB * SEQP * DIMP);
  float* scores = alF((size_t)NB * NH * SEQ * SEQ);  // also ff32 + ffb region
  hb[0] = alH((size_t)NB * SEQP * DIMP);
  hb[1] = alH((size_t)NB * SEQS * DIME);
  ushort* qt = alH((size_t)NB * SEQP * HH);
  ushort* kt = alH((size_t)NB * SEQP * HH);
  ushort* vt = alH((size_t)NB * SEQP * HH);
  ushort* qj = alH((size_t)NB * NH * SEQ * DH);
  ushort* kj = alH((size_t)NB * NH * SEQ * DH);
  ushort* vjT = alH((size_t)NB * NH * DH * SEQ);
  ushort* att2b = alH((size_t)NB * SEQ * HH);
  ushort* wT = alH((size_t)FFP * DIMP);  // largest weight, shared scratch
  if (off > ws_size) return;  // fail loudly (output stays poisoned)

  float* ff32 = scores;                                   // [M][F] gate result (f32)
  ushort* ffb = (ushort*)(scores + (size_t)NB * SEQP * FFP);  // [M][F] bf16 gelu*up

  copy4_k<<<(NB * SEQP * DIMP / 4) / 256, 256, 0, stream>>>((float4*)xs[0], (const float4*)emb_p);
  copy4_k<<<(NB * SEQS * DIME / 4) / 256, 256, 0, stream>>>((float4*)xs[1], (const float4*)emb_e);
  rope_tab_k<<<NB * SEQ, DH, 0, stream>>>(pos, cosb, sinb);

  for (int l = 0; l < NL; ++l) {
    for (int i = 0; i < 2; ++i) {
      int D = Ds[i], Si = Sis[i], M = NB * Si;
      const float* a1 = ada1[i] + (size_t)l * D * 2 * D;
      ada_k<<<dim3(2 * D / 256, 8), 256, 0, stream>>>(cond[i], a1, part, D, 2 * D);
      ada_red_k<<<4 * D / 256, 256, 0, stream>>>(part, sg[i], 2 * D, 8);
      rms_k<ushort><<<M, 256, 0, stream>>>(xs[i], sg[i], hb[i], D, Si);
      const float* W3[3] = {wq[i] + (size_t)l * D * HH, wk[i] + (size_t)l * D * HH,
                            wv[i] + (size_t)l * D * HH};
      ushort* out3[3] = {qt, kt, vt};
      for (int j = 0; j < 3; ++j) {
        wconv_k<<<dim3(HH / 64, D / 64), 256, 0, stream>>>(W3[j], wT, HH, D);
        bgemm_k<1><<<dim3(HH / 128, M / 128, 1), 256, 0, stream>>>(
            hb[i], wT, nullptr, out3[j], D, D, D, HH, 0, 0, 0, 0, 0, 0, 1);
      }
      rope_qk_k<<<dim3(M, HH / 256), 256, 0, stream>>>(qt, kt, cosb, sinb, qj, kj, Si, ofss[i]);
      vtrans_k<<<dim3(Si / 64, DH / 64, NB * NH), 256, 0, stream>>>(vt, vjT, Si, ofss[i]);
    }
    // scores = q k^T (f32), softmax -> bf16 probs in place, att = P v (bf16)
    bgemm_k<0><<<dim3(SEQ / 128, SEQ / 128, NB * NH), 256, 0, stream>>>(
        qj, kj, scores, nullptr, DH, DH, DH, SEQ,
        (long)SEQ * DH, 0, (long)SEQ * DH, 0, (long)SEQ * SEQ, 0, 1);
    softmax_k<<<dim3(SEQ, NB * NH), 256, 0, stream>>>(scores);
    bgemm_k<1><<<dim3(DH / 128, SEQ / 128, NB * NH), 256, 0, stream>>>(
        (const ushort*)scores, vjT, nullptr, att2b, SEQ, 2 * SEQ, SEQ, HH,
        (long)2 * NH * SEQ * SEQ, (long)2 * SEQ * SEQ,
        (long)NH * DH * SEQ, (long)DH * SEQ,
        (long)SEQ * HH, (long)DH, NH);
    for (int i = 0; i < 2; ++i) {
      int D = Ds[i], F = Fs[i], Si = Sis[i], M = NB * Si;
      wconv_k<<<dim3(D / 64, HH / 64), 256, 0, stream>>>(wo[i] + (size_t)l * HH * D, wT, D, HH);
      bgemm_k<0><<<dim3(D / 128, Si / 128, NB), 256, 0, stream>>>(
          att2b + (long)ofss[i] * HH, wT, tmp, nullptr, HH, HH, HH, D,
          (long)SEQ * HH, 0, 0, 0, (long)Si * D, 0, 1);
      gated_add_k<<<M * D / 256, 256, 0, stream>>>(xs[i], tmp, sg[i] + D, D, Si);
      const float* a2 = ada2[i] + (size_t)l * D * 2 * D;
      ada_k<<<dim3(2 * D / 256, 8), 256, 0, stream>>>(cond[i], a2, part, D, 2 * D);
      ada_red_k<<<4 * D / 256, 256, 0, stream>>>(part, sg[i], 2 * D, 8);
      rms_k<ushort><<<M, 256, 0, stream>>>(xs[i], sg[i], hb[i], D, Si);
      wconv_k<<<dim3(F / 64, D / 64), 256, 0, stream>>>(wg[i] + (size_t)l * D * F, wT, F, D);
      bgemm_k<0><<<dim3(F / 128, M / 128, 1), 256, 0, stream>>>(
          hb[i], wT, ff32, nullptr, D, D, D, F, 0, 0, 0, 0, 0, 0, 1);
      wconv_k<<<dim3(F / 64, D / 64), 256, 0, stream>>>(wu[i] + (size_t)l * D * F, wT, F, D);
      bgemm_k<2><<<dim3(F / 128, M / 128, 1), 256, 0, stream>>>(
          hb[i], wT, ff32, ffb, D, D, D, F, 0, 0, 0, 0, 0, 0, 1);
      wconv_k<<<dim3(D / 64, F / 64), 256, 0, stream>>>(wd[i] + (size_t)l * F * D, wT, D, F);
      bgemm_k<0><<<dim3(D / 128, M / 128, 1), 256, 0, stream>>>(
          ffb, wT, tmp, nullptr, F, F, F, D, 0, 0, 0, 0, 0, 0, 1);
      gated_add_k<<<M * D / 256, 256, 0, stream>>>(xs[i], tmp, sg[i] + D, D, Si);
    }
  }
  float* outp = (float*)d_out;
  for (int i = 0; i < 2; ++i) {
    int D = Ds[i], Si = Sis[i];
    ada_k<<<dim3(2 * D / 256, 8), 256, 0, stream>>>(cond[i], adaF[i], part, D, 2 * D);
    ada_red_k<<<4 * D / 256, 256, 0, stream>>>(part, sg[i], 2 * D, 8);
    rms_k<float><<<NB * Si, 256, 0, stream>>>(xs[i], sg[i], outp, D, Si);
    outp += (size_t)NB * Si * D;
  }
}

// Round 3
// 2432.557 us; speedup vs baseline: 5.0705x; 1.2233x over previous
//
#include <hip/hip_runtime.h>
#include <math.h>

namespace {

constexpr int NL = 2, NH = 8, DH = 256;
constexpr int NB = 2, SEQP = 1024, SEQS = 256, SEQ = SEQP + SEQS;
constexpr int DIMP = 2048, DIME = 1024, FFP = 8192, FFE = 4096;
constexpr int HH = NH * DH;  // 2048
constexpr int QKVN = 3 * HH; // 6144

typedef __attribute__((ext_vector_type(8))) short bf16x8;
typedef __attribute__((ext_vector_type(4))) float f32x4;

__device__ inline ushort f2b(float f) {
  union { float f; unsigned u; } x{f};
  unsigned r = (x.u + 0x7FFFu + ((x.u >> 16) & 1u)) >> 16;
  return (ushort)r;
}
__device__ inline float b2f(ushort u) {
  union { unsigned u; float f; } x{(unsigned)u << 16};
  return x.f;
}
__device__ inline void stv(float* p, float v) { *p = v; }
__device__ inline void stv(ushort* p, float v) { *p = f2b(v); }

__device__ inline void gld16(const void* g, void* l) {
  __builtin_amdgcn_global_load_lds(
      (const __attribute__((address_space(1))) void*)g,
      (__attribute__((address_space(3))) void*)l, 16, 0, 0);
}

// ---------------- elementwise / small kernels ----------------

__global__ void copy4_k(float4* __restrict__ dst, const float4* __restrict__ src) {
  long i = (long)blockIdx.x * blockDim.x + threadIdx.x;
  dst[i] = src[i];
}

__global__ void rope_tab_k(const int* __restrict__ pos, float* __restrict__ cosb,
                           float* __restrict__ sinb) {
  long bs = blockIdx.x;
  int d = threadIdx.x;
  int i = d & (DH / 2 - 1);
  float inv = expf(-(2.0f * (float)i / (float)DH) * logf(10000.0f));
  float ang = (float)pos[bs] * inv;
  cosb[bs * DH + d] = cosf(ang);
  sinb[bs * DH + d] = sinf(ang);
}

__global__ __launch_bounds__(256) void ada_k(const float* __restrict__ cond,
    const float* __restrict__ W, float* __restrict__ part, int D, int twoD) {
  __shared__ float lc[2 * 2048];
  int t = threadIdx.x;
  int j = blockIdx.x * 256 + t;
  int chunk = blockIdx.y;
  int cl = D / gridDim.y;
  int d0 = chunk * cl;
  for (int i = t; i < 2 * D; i += 256) lc[i] = cond[i];
  __syncthreads();
  float a0 = 0.f, a1 = 0.f;
  for (int d = d0; d < d0 + cl; ++d) {
    float wvv = W[(long)d * twoD + j];
    a0 = fmaf(lc[d], wvv, a0);
    a1 = fmaf(lc[D + d], wvv, a1);
  }
  part[((long)chunk * 2 + 0) * twoD + j] = a0;
  part[((long)chunk * 2 + 1) * twoD + j] = a1;
}

__global__ void ada_red_k(const float* __restrict__ part, float* __restrict__ sg,
                          int twoD, int nch) {
  int idx = blockIdx.x * 256 + threadIdx.x;
  int b = idx / twoD, j = idx - b * twoD;
  float s = 0.f;
  for (int c = 0; c < nch; ++c) s += part[((long)c * 2 + b) * twoD + j];
  sg[(long)b * twoD + j] = s;
}

template <typename OT>
__global__ __launch_bounds__(256) void rms_k(const float* __restrict__ x,
    const float* __restrict__ sg, OT* __restrict__ out, int D, int rowsPerB) {
  long row = blockIdx.x;
  int b = (int)(row / rowsPerB);
  const float* xr = x + row * (long)D;
  OT* po = out + row * (long)D;
  const float* sc = sg + (long)b * 2 * D;
  int t = threadIdx.x;
  float ss = 0.f;
  for (int i = t; i < D; i += 256) { float v = xr[i]; ss = fmaf(v, v, ss); }
  for (int o = 32; o; o >>= 1) ss += __shfl_xor(ss, o);
  __shared__ float wr[4];
  if ((t & 63) == 0) wr[t >> 6] = ss;
  __syncthreads();
  float rs = rsqrtf((wr[0] + wr[1] + wr[2] + wr[3]) / (float)D + 1e-6f);
  for (int i = t; i < D; i += 256) stv(po + i, xr[i] * rs * (1.f + sc[i]));
}

__global__ void gated_add_k(float* __restrict__ x, const float* __restrict__ y,
                            const float* __restrict__ g, int D, int rowsPerB) {
  long idx = (long)blockIdx.x * 256 + threadIdx.x;
  int d = (int)(idx % D);
  int b = (int)(idx / ((long)rowsPerB * D));
  x[idx] = fmaf(y[idx], g[(long)b * 2 * D + d], x[idx]);
}

// fp32 [K][N] -> bf16 [N][K] transpose-convert
__global__ __launch_bounds__(256) void wconv_k(const float* __restrict__ in,
    ushort* __restrict__ out, int N, int K) {
  __shared__ float tile[64][65];
  int n0 = blockIdx.x << 6, k0 = blockIdx.y << 6;
  int t = threadIdx.x, r = t >> 4, c4 = (t & 15) << 2;
#pragma unroll
  for (int rr = 0; rr < 64; rr += 16) {
    float4 v = *(const float4*)(in + (long)(k0 + r + rr) * N + n0 + c4);
    tile[r + rr][c4 + 0] = v.x; tile[r + rr][c4 + 1] = v.y;
    tile[r + rr][c4 + 2] = v.z; tile[r + rr][c4 + 3] = v.w;
  }
  __syncthreads();
#pragma unroll
  for (int rr = 0; rr < 64; rr += 16) {
    int n = r + rr;
    ushort4 o;
    o.x = f2b(tile[c4 + 0][n]); o.y = f2b(tile[c4 + 1][n]);
    o.z = f2b(tile[c4 + 2][n]); o.w = f2b(tile[c4 + 3][n]);
    *(ushort4*)(out + (long)(n0 + n) * K + k0 + c4) = o;
  }
}

// fused qkv bf16 [B*Si][QKVN] -> RoPE -> qj/kj bf16 [B,NH,SEQ,DH]
__global__ __launch_bounds__(256) void rope_qk_k(const ushort* __restrict__ qkv,
    const float* __restrict__ cosb, const float* __restrict__ sinb,
    ushort* __restrict__ qj, ushort* __restrict__ kj, int Si, int ofs) {
  long bs = blockIdx.x;
  int b = (int)(bs / Si), s = (int)(bs % Si);
  int c = blockIdx.y * 256 + threadIdx.x;
  int h = c >> 8, hd = c & 255;
  long tin = bs * (long)QKVN;
  float q = b2f(qkv[tin + c]), k = b2f(qkv[tin + HH + c]);
  float qp = b2f(qkv[tin + (c ^ 128)]), kp = b2f(qkv[tin + HH + (c ^ 128)]);
  long sgi = ((long)b * SEQ + ofs + s) * DH + hd;
  float cv = cosb[sgi], sv = sinb[sgi];
  float qr = (hd < 128) ? -qp : qp, kr = (hd < 128) ? -kp : kp;
  long o = (((long)b * NH + h) * SEQ + ofs + s) * (long)DH + hd;
  qj[o] = f2b(fmaf(q, cv, qr * sv));
  kj[o] = f2b(fmaf(k, cv, kr * sv));
}

// v (cols [2*HH,3*HH) of qkv) [B*Si][QKVN] -> vjT bf16 [B,NH,DH,SEQ]
__global__ __launch_bounds__(256) void vtrans_k(const ushort* __restrict__ qkv,
    ushort* __restrict__ vjT, int Si, int ofs) {
  __shared__ ushort tile[64][80];
  int z = blockIdx.z, b = z >> 3, h = z & 7;
  int s0 = blockIdx.x << 6, d0 = blockIdx.y << 6;
  int t = threadIdx.x, r = t >> 3, c8 = (t & 7) << 3;
#pragma unroll
  for (int rr = 0; rr < 64; rr += 32) {
    const ushort* src = qkv + (long)(b * Si + s0 + r + rr) * QKVN + 2 * HH + h * DH + d0 + c8;
    *(uint4*)&tile[r + rr][c8] = *(const uint4*)src;
  }
  __syncthreads();
#pragma unroll
  for (int rr = 0; rr < 64; rr += 32) {
    int drow = r + rr;
    ushort o[8];
#pragma unroll
    for (int j = 0; j < 8; ++j) o[j] = tile[c8 + j][drow];
    *(uint4*)(vjT + ((long)(b * NH + h) * DH + d0 + drow) * SEQ + ofs + s0 + c8) =
        *(const uint4*)o;
  }
}

// softmax over fp32 scores row; writes bf16 probs in place (first half of row)
__global__ __launch_bounds__(256) void softmax_k(float* __restrict__ scores) {
  float* p = scores + (long)blockIdx.y * SEQ * SEQ + (long)blockIdx.x * SEQ;
  ushort* po = (ushort*)p;
  int t = threadIdx.x;
  float v[5];
  float mx = -3.4e38f;
#pragma unroll
  for (int i = 0; i < 5; ++i) { v[i] = p[t + i * 256] * 0.0625f; mx = fmaxf(mx, v[i]); }
  for (int o = 32; o; o >>= 1) mx = fmaxf(mx, __shfl_xor(mx, o));
  __shared__ float wr[4];
  if ((t & 63) == 0) wr[t >> 6] = mx;
  __syncthreads();
  mx = fmaxf(fmaxf(wr[0], wr[1]), fmaxf(wr[2], wr[3]));
  __syncthreads();
  float s = 0.f;
#pragma unroll
  for (int i = 0; i < 5; ++i) { v[i] = expf(v[i] - mx); s += v[i]; }
  for (int o = 32; o; o >>= 1) s += __shfl_xor(s, o);
  if ((t & 63) == 0) wr[t >> 6] = s;
  __syncthreads();
  float inv = 1.f / (wr[0] + wr[1] + wr[2] + wr[3]);
#pragma unroll
  for (int i = 0; i < 5; ++i) po[t + i * 256] = f2b(v[i] * inv);
}

// out[m][f] = gelu(in[m][f]) * in[m][F+f]; in rows 2F wide, bf16
__global__ __launch_bounds__(256) void gelumul_k(const ushort* __restrict__ in,
    ushort* __restrict__ out, int F) {
  long v = (long)blockIdx.x * 256 + threadIdx.x;
  int fv = F >> 3;
  long m = v / fv; int f8 = (int)(v % fv) << 3;
  const ushort* gp = in + m * 2 * F + f8;
  uint4 gv = *(const uint4*)gp;
  uint4 uv = *(const uint4*)(gp + F);
  const ushort* gs = (const ushort*)&gv;
  const ushort* us = (const ushort*)&uv;
  ushort ov[8];
#pragma unroll
  for (int j = 0; j < 8; ++j) {
    float g = b2f(gs[j]);
    float ge = 0.5f * g * (1.f + tanhf(0.7978845608028654f * fmaf(0.044715f * g, g * g, g)));
    ov[j] = f2b(ge * b2f(us[j]));
  }
  *(uint4*)(out + m * F + f8) = *(const uint4*)ov;
}

// out[i] = sum_c in[c*MN + i]  (float4 vectorized; MN % 1024 == 0)
__global__ void redsum_k(const float4* __restrict__ in, float4* __restrict__ out,
                         long MN4, int ns) {
  long i = (long)blockIdx.x * 256 + threadIdx.x;
  float4 s = in[i];
  for (int c = 1; c < ns; ++c) {
    float4 v = in[(long)c * MN4 + i];
    s.x += v.x; s.y += v.y; s.z += v.z; s.w += v.w;
  }
  out[i] = s;
}

// ---------------- bf16 MFMA GEMM, 128x128 (m97 structure) ----------------
// C = A[M,K] @ B^T, B is [N][K] bf16. EPI: 0 = f32 store, 1 = bf16 store.
template <int EPI>
__global__ __launch_bounds__(256) void bgemm_k(
    const ushort* __restrict__ A, const ushort* __restrict__ B,
    float* __restrict__ Cf, ushort* __restrict__ Cb, int K,
    int lda, int ldb, int ldc,
    long sA1, long sA2, long sB1, long sB2, long sC1, long sC2, int bdiv) {
  __shared__ ushort As[128 * 32];
  __shared__ ushort Bs[128 * 32];
  int t = threadIdx.x;
  int z = blockIdx.z, z1 = z / bdiv, z2 = z % bdiv;
  A += z1 * sA1 + z2 * sA2;
  B += z1 * sB1 + z2 * sB2;
  long cofs = z1 * sC1 + z2 * sC2;
  int m0 = blockIdx.y * 128, n0 = blockIdx.x * 128;
  int srow = t >> 2, scol = (t & 3) << 3;
  const ushort* gA0 = A + (long)(m0 + srow) * lda + scol;
  const ushort* gA1 = A + (long)(m0 + srow + 64) * lda + scol;
  const ushort* gB0 = B + (long)(n0 + srow) * ldb + scol;
  const ushort* gB1 = B + (long)(n0 + srow + 64) * ldb + scol;
  ushort* lA0 = &As[srow * 32 + scol];
  ushort* lA1 = &As[(srow + 64) * 32 + scol];
  ushort* lB0 = &Bs[srow * 32 + scol];
  ushort* lB1 = &Bs[(srow + 64) * 32 + scol];
  int lane = t & 63;
  int wm = ((t >> 6) & 1) << 6, wn = (t >> 7) << 6;
  int fr = lane & 15, fk = (lane >> 4) << 3;
  f32x4 acc[4][4] = {};
  for (int k0 = 0; k0 < K; k0 += 32) {
    if (k0) __syncthreads();
    gld16(gA0 + k0, lA0);
    gld16(gA1 + k0, lA1);
    gld16(gB0 + k0, lB0);
    gld16(gB1 + k0, lB1);
    __syncthreads();
    bf16x8 a[4], b[4];
#pragma unroll
    for (int m = 0; m < 4; ++m)
      a[m] = *(const bf16x8*)&As[(wm + m * 16 + fr) * 32 + fk];
#pragma unroll
    for (int n = 0; n < 4; ++n)
      b[n] = *(const bf16x8*)&Bs[(wn + n * 16 + fr) * 32 + fk];
#pragma unroll
    for (int m = 0; m < 4; ++m)
#pragma unroll
      for (int n = 0; n < 4; ++n)
        acc[m][n] = __builtin_amdgcn_mfma_f32_16x16x32_bf16(a[m], b[n], acc[m][n], 0, 0, 0);
  }
  int cr = (lane >> 4) << 2, cc = lane & 15;
#pragma unroll
  for (int m = 0; m < 4; ++m) {
    int row = m0 + wm + m * 16 + cr;
#pragma unroll
    for (int n = 0; n < 4; ++n) {
      int col = n0 + wn + n * 16 + cc;
#pragma unroll
      for (int r = 0; r < 4; ++r) {
        long idx = cofs + (long)(row + r) * ldc + col;
        if (EPI == 0) Cf[idx] = acc[m][n][r];
        else Cb[idx] = f2b(acc[m][n][r]);
      }
    }
  }
}

// ---------------- bf16 MFMA GEMM, 256x256, 4-deep ring pipeline ----------------
// 512 threads = 8 waves (2M x 4N); per-wave 128x64 output; BK=32.
// LDS: 4 ring buffers x (A 16KB + B 16KB) = 128 KiB -> 1 block/CU.
// Counted s_waitcnt vmcnt + raw s_barrier (loads stay in flight across barriers).
// XOR slot-swizzle: physical slot p of row r holds global slot p ^ ((r>>1)&3)
// (pre-swizzled global source, linear gld_lds dest, swizzled ds_read).
// Requires K % 32 == 0, K/32 >= 3, M % 256 == 0, N % 256 == 0.
template <int EPI>
__global__ __launch_bounds__(512, 2) void bgemm256_k(
    const ushort* __restrict__ A, const ushort* __restrict__ B,
    float* __restrict__ Cf, ushort* __restrict__ Cb, int K,
    int lda, int ldb, int ldc,
    long sA1, long sA2, long sB1, long sB2, long sC1, long sC2, int bdiv) {
  __shared__ ushort As[4][256 * 32];
  __shared__ ushort Bs[4][256 * 32];
  int t = threadIdx.x;
  int z = blockIdx.z, z1 = z / bdiv, z2 = z % bdiv;
  A += z1 * sA1 + z2 * sA2;
  B += z1 * sB1 + z2 * sB2;
  long cofs = z1 * sC1 + z2 * sC2;
  // bijective XCD-aware swizzle over the (x,y) grid (m204)
  int nx = gridDim.x;
  int nwg = nx * gridDim.y;
  int wg = blockIdx.y * nx + blockIdx.x;
  int q = nwg >> 3, r = nwg & 7;
  int xcd = wg & 7, wi = wg >> 3;
  int swz = (xcd < r ? xcd * (q + 1) : r * (q + 1) + (xcd - r) * q) + wi;
  int n0 = (swz % nx) << 8;
  int m0 = (swz / nx) << 8;

  int srow = t >> 2;
  int gc = ((t & 3) ^ ((srow >> 1) & 3)) << 3;  // pre-swizzled source col
  const ushort* ga0 = A + (long)(m0 + srow) * lda + gc;
  const ushort* ga1 = A + (long)(m0 + 128 + srow) * lda + gc;
  const ushort* gb0 = B + (long)(n0 + srow) * ldb + gc;
  const ushort* gb1 = B + (long)(n0 + 128 + srow) * ldb + gc;

  int lane = t & 63, wid = t >> 6;
  int wm = wid >> 2, wn = wid & 3;
  int fr = lane & 15, sl = lane >> 4;

  int aoff[8], boff[4];
#pragma unroll
  for (int m = 0; m < 8; ++m) {
    int row = wm * 128 + m * 16 + fr;
    aoff[m] = row * 32 + ((sl ^ ((row >> 1) & 3)) << 3);
  }
#pragma unroll
  for (int n = 0; n < 4; ++n) {
    int row = wn * 64 + n * 16 + fr;
    boff[n] = row * 32 + ((sl ^ ((row >> 1) & 3)) << 3);
  }

  f32x4 acc[8][4] = {};
  int nt = K >> 5;

#define STAGE(ti) { int b_ = (ti) & 3; int k_ = (ti) << 5;        \
    gld16(ga0 + k_, &As[b_][t * 8]);                              \
    gld16(ga1 + k_, &As[b_][4096 + t * 8]);                       \
    gld16(gb0 + k_, &Bs[b_][t * 8]);                              \
    gld16(gb1 + k_, &Bs[b_][4096 + t * 8]); }

  STAGE(0); STAGE(1); STAGE(2);
  for (int ti = 0; ti < nt; ++ti) {
    // tile ti must have landed: allow only loads of tiles > ti outstanding
    if (ti + 2 < nt)      asm volatile("s_waitcnt vmcnt(8)" ::: "memory");
    else if (ti + 1 < nt) asm volatile("s_waitcnt vmcnt(4)" ::: "memory");
    else                  asm volatile("s_waitcnt vmcnt(0)" ::: "memory");
    __builtin_amdgcn_s_barrier();
    // safe: every wave's reads of this buffer were lgkm-drained before its
    // MFMAs last round, which precede the barrier above.
    if (ti + 3 < nt) STAGE(ti + 3);
    int bu = ti & 3;
    bf16x8 av[8], bv[4];
#pragma unroll
    for (int m = 0; m < 8; ++m) av[m] = *(const bf16x8*)&As[bu][aoff[m]];
#pragma unroll
    for (int n = 0; n < 4; ++n) bv[n] = *(const bf16x8*)&Bs[bu][boff[n]];
    __builtin_amdgcn_s_setprio(1);
#pragma unroll
    for (int m = 0; m < 8; ++m)
#pragma unroll
      for (int n = 0; n < 4; ++n)
        acc[m][n] = __builtin_amdgcn_mfma_f32_16x16x32_bf16(av[m], bv[n], acc[m][n], 0, 0, 0);
    __builtin_amdgcn_s_setprio(0);
  }
#undef STAGE

  int cr = sl << 2, cc = fr;
#pragma unroll
  for (int m = 0; m < 8; ++m) {
    int row = m0 + wm * 128 + m * 16 + cr;
#pragma unroll
    for (int n = 0; n < 4; ++n) {
      int col = n0 + wn * 64 + n * 16 + cc;
#pragma unroll
      for (int rr = 0; rr < 4; ++rr) {
        long idx = cofs + (long)(row + rr) * ldc + col;
        if (EPI == 0) Cf[idx] = acc[m][n][rr];
        else Cb[idx] = f2b(acc[m][n][rr]);
      }
    }
  }
}

}  // namespace

extern "C" void kernel_launch(void* const* d_in, const int* in_sizes, int n_in,
                              void* d_out, int out_size, void* d_ws, size_t ws_size,
                              hipStream_t stream) {
  (void)in_sizes; (void)n_in; (void)out_size;
  const float* emb_p = (const float*)d_in[0];
  const float* emb_e = (const float*)d_in[1];
  const float* cond[2] = {(const float*)d_in[2], (const float*)d_in[3]};
  const float* ada1[2] = {(const float*)d_in[4], (const float*)d_in[14]};
  const float* ada2[2] = {(const float*)d_in[5], (const float*)d_in[15]};
  const float* adaF[2] = {(const float*)d_in[6], (const float*)d_in[16]};
  const float* wq[2] = {(const float*)d_in[7], (const float*)d_in[17]};
  const float* wk[2] = {(const float*)d_in[8], (const float*)d_in[18]};
  const float* wv[2] = {(const float*)d_in[9], (const float*)d_in[19]};
  const float* wo[2] = {(const float*)d_in[10], (const float*)d_in[20]};
  const float* wg[2] = {(const float*)d_in[11], (const float*)d_in[21]};
  const float* wu[2] = {(const float*)d_in[12], (const float*)d_in[22]};
  const float* wd[2] = {(const float*)d_in[13], (const float*)d_in[23]};
  const int* pos = (const int*)d_in[24];

  const int Ds[2] = {DIMP, DIME};
  const int Fs[2] = {FFP, FFE};
  const int Sis[2] = {SEQP, SEQS};
  const int ofss[2] = {0, SEQP};

  char* base = (char*)d_ws;
  size_t off = 0;
  auto alF = [&](size_t n) { float* r = (float*)(base + off); off += (n * 4 + 255) & ~(size_t)255; return r; };
  auto alH = [&](size_t n) { ushort* r = (ushort*)(base + off); off += (n * 2 + 255) & ~(size_t)255; return r; };

  float* xs[2]; ushort* hb[2]; float* sg[2];
  xs[0] = alF((size_t)NB * SEQP * DIMP);
  xs[1] = alF((size_t)NB * SEQS * DIME);
  float* cosb = alF((size_t)NB * SEQ * DH);
  float* sinb = alF((size_t)NB * SEQ * DH);
  sg[0] = alF((size_t)NB * 2 * DIMP);
  sg[1] = alF((size_t)NB * 2 * DIME);
  float* part = alF((size_t)8 * 2 * 2 * DIMP);
  float* tmp = alF((size_t)NB * SEQP * DIMP);
  float* scores = alF((size_t)NB * NH * SEQ * SEQ);  // 105MB; also pbuf/ffb2/ffb
  hb[0] = alH((size_t)NB * SEQP * DIMP);
  hb[1] = alH((size_t)NB * SEQS * DIME);
  ushort* qkvt = alH((size_t)NB * SEQP * QKVN);
  ushort* qj = alH((size_t)NB * NH * SEQ * DH);
  ushort* kj = alH((size_t)NB * NH * SEQ * DH);
  ushort* vjT = alH((size_t)NB * NH * DH * SEQ);
  ushort* att2b = alH((size_t)NB * SEQ * HH);
  ushort* wT = alH((size_t)2 * FFP * DIMP);  // fused gate|up is the largest
  if (off > ws_size) return;  // fail loudly (output stays poisoned)

  float* pbuf = scores;                    // split-K partials (<= 67MB)
  ushort* ffb2 = (ushort*)scores;          // [M][2F] raw gate|up (<= 67MB)
  ushort* ffb = (ushort*)((char*)scores + (size_t)70 * 1024 * 1024);  // [M][F]

  copy4_k<<<(NB * SEQP * DIMP / 4) / 256, 256, 0, stream>>>((float4*)xs[0], (const float4*)emb_p);
  copy4_k<<<(NB * SEQS * DIME / 4) / 256, 256, 0, stream>>>((float4*)xs[1], (const float4*)emb_e);
  rope_tab_k<<<NB * SEQ, DH, 0, stream>>>(pos, cosb, sinb);

  for (int l = 0; l < NL; ++l) {
    for (int i = 0; i < 2; ++i) {
      int D = Ds[i], Si = Sis[i], M = NB * Si;
      const float* a1 = ada1[i] + (size_t)l * D * 2 * D;
      ada_k<<<dim3(2 * D / 256, 8), 256, 0, stream>>>(cond[i], a1, part, D, 2 * D);
      ada_red_k<<<4 * D / 256, 256, 0, stream>>>(part, sg[i], 2 * D, 8);
      rms_k<ushort><<<M, 256, 0, stream>>>(xs[i], sg[i], hb[i], D, Si);
      // fused QKV weight: wT = [3*HH][D] bf16
      const float* W3[3] = {wq[i] + (size_t)l * D * HH, wk[i] + (size_t)l * D * HH,
                            wv[i] + (size_t)l * D * HH};
      for (int j = 0; j < 3; ++j)
        wconv_k<<<dim3(HH / 64, D / 64), 256, 0, stream>>>(W3[j], wT + (size_t)j * HH * D, HH, D);
      if (i == 0)
        bgemm256_k<1><<<dim3(QKVN / 256, M / 256, 1), 512, 0, stream>>>(
            hb[i], wT, nullptr, qkvt, D, D, D, QKVN, 0, 0, 0, 0, 0, 0, 1);
      else
        bgemm_k<1><<<dim3(QKVN / 128, M / 128, 1), 256, 0, stream>>>(
            hb[i], wT, nullptr, qkvt, D, D, D, QKVN, 0, 0, 0, 0, 0, 0, 1);
      rope_qk_k<<<dim3(M, HH / 256), 256, 0, stream>>>(qkvt, cosb, sinb, qj, kj, Si, ofss[i]);
      vtrans_k<<<dim3(Si / 64, DH / 64, NB * NH), 256, 0, stream>>>(qkvt, vjT, Si, ofss[i]);
    }
    // joint attention
    bgemm256_k<0><<<dim3(SEQ / 256, SEQ / 256, NB * NH), 512, 0, stream>>>(
        qj, kj, scores, nullptr, DH, DH, DH, SEQ,
        (long)SEQ * DH, 0, (long)SEQ * DH, 0, (long)SEQ * SEQ, 0, 1);
    softmax_k<<<dim3(SEQ, NB * NH), 256, 0, stream>>>(scores);
    bgemm_k<1><<<dim3(DH / 128, SEQ / 128, NB * NH), 256, 0, stream>>>(
        (const ushort*)scores, vjT, nullptr, att2b, SEQ, 2 * SEQ, SEQ, HH,
        (long)2 * NH * SEQ * SEQ, (long)2 * SEQ * SEQ,
        (long)NH * DH * SEQ, (long)DH * SEQ,
        (long)SEQ * HH, (long)DH, NH);
    for (int i = 0; i < 2; ++i) {
      int D = Ds[i], F = Fs[i], Si = Sis[i], M = NB * Si;
      // WO, split-K x4 (Kc = HH/4 = 512) into pbuf, then reduce -> tmp
      wconv_k<<<dim3(D / 64, HH / 64), 256, 0, stream>>>(wo[i] + (size_t)l * HH * D, wT, D, HH);
      if (i == 0)
        bgemm256_k<0><<<dim3(D / 256, Si / 256, NB * 4), 512, 0, stream>>>(
            att2b, wT, pbuf, nullptr, 512, HH, HH, D,
            (long)SEQ * HH, 512, 0, 512, (long)Si * D, (long)M * D, 4);
      else
        bgemm_k<0><<<dim3(D / 128, Si / 128, NB * 4), 256, 0, stream>>>(
            att2b + (size_t)ofss[i] * HH, wT, pbuf, nullptr, 512, HH, HH, D,
            (long)SEQ * HH, 512, 0, 512, (long)Si * D, (long)M * D, 4);
      redsum_k<<<M * D / 4 / 256, 256, 0, stream>>>((const float4*)pbuf, (float4*)tmp,
                                                    (long)M * D / 4, 4);
      gated_add_k<<<M * D / 256, 256, 0, stream>>>(xs[i], tmp, sg[i] + D, D, Si);
      const float* a2 = ada2[i] + (size_t)l * D * 2 * D;
      ada_k<<<dim3(2 * D / 256, 8), 256, 0, stream>>>(cond[i], a2, part, D, 2 * D);
      ada_red_k<<<4 * D / 256, 256, 0, stream>>>(part, sg[i], 2 * D, 8);
      rms_k<ushort><<<M, 256, 0, stream>>>(xs[i], sg[i], hb[i], D, Si);
      // fused gate|up -> ffb2 [M][2F] bf16, then gelu*up -> ffb [M][F]
      wconv_k<<<dim3(F / 64, D / 64), 256, 0, stream>>>(wg[i] + (size_t)l * D * F, wT, F, D);
      wconv_k<<<dim3(F / 64, D / 64), 256, 0, stream>>>(wu[i] + (size_t)l * D * F,
                                                        wT + (size_t)F * D, F, D);
      if (i == 0)
        bgemm256_k<1><<<dim3(2 * F / 256, M / 256, 1), 512, 0, stream>>>(
            hb[i], wT, nullptr, ffb2, D, D, D, 2 * F, 0, 0, 0, 0, 0, 0, 1);
      else
        bgemm_k<1><<<dim3(2 * F / 128, M / 128, 1), 256, 0, stream>>>(
            hb[i], wT, nullptr, ffb2, D, D, D, 2 * F, 0, 0, 0, 0, 0, 0, 1);
      gelumul_k<<<(long)M * F / 8 / 256, 256, 0, stream>>>(ffb2, ffb, F);
      // down, split-K into pbuf, reduce -> tmp
      wconv_k<<<dim3(D / 64, F / 64), 256, 0, stream>>>(wd[i] + (size_t)l * F * D, wT, D, F);
      if (i == 0)
        bgemm256_k<0><<<dim3(D / 256, M / 256, 4), 512, 0, stream>>>(
            ffb, wT, pbuf, nullptr, F / 4, F, F, D,
            0, F / 4, 0, F / 4, 0, (long)M * D, 4);
      else
        bgemm_k<0><<<dim3(D / 128, M / 128, 8), 256, 0, stream>>>(
            ffb, wT, pbuf, nullptr, F / 8, F, F, D,
            0, F / 8, 0, F / 8, 0, (long)M * D, 8);
      redsum_k<<<M * D / 4 / 256, 256, 0, stream>>>((const float4*)pbuf, (float4*)tmp,
                                                    (long)M * D / 4, i == 0 ? 4 : 8);
      gated_add_k<<<M * D / 256, 256, 0, stream>>>(xs[i], tmp, sg[i] + D, D, Si);
    }
  }
  float* outp = (float*)d_out;
  for (int i = 0; i < 2; ++i) {
    int D = Ds[i], Si = Sis[i];
    ada_k<<<dim3(2 * D / 256, 8), 256, 0, stream>>>(cond[i], adaF[i], part, D, 2 * D);
    ada_red_k<<<4 * D / 256, 256, 0, stream>>>(part, sg[i], 2 * D, 8);
    rms_k<float><<<NB * Si, 256, 0, stream>>>(xs[i], sg[i], outp, D, Si);
    outp += (size_t)NB * Si * D;
  }
}

// Round 4
// 2208.032 us; speedup vs baseline: 5.5861x; 1.1017x over previous
//
#include <hip/hip_runtime.h>
#include <math.h>

namespace {

constexpr int NL = 2, NH = 8, DH = 256;
constexpr int NB = 2, SEQP = 1024, SEQS = 256, SEQ = SEQP + SEQS;
constexpr int DIMP = 2048, DIME = 1024, FFP = 8192, FFE = 4096;
constexpr int HH = NH * DH;  // 2048
constexpr int QKVN = 3 * HH; // 6144

typedef __attribute__((ext_vector_type(8))) short bf16x8;
typedef __attribute__((ext_vector_type(4))) float f32x4;

__device__ inline ushort f2b(float f) {
  union { float f; unsigned u; } x{f};
  unsigned r = (x.u + 0x7FFFu + ((x.u >> 16) & 1u)) >> 16;
  return (ushort)r;
}
__device__ inline float b2f(ushort u) {
  union { unsigned u; float f; } x{(unsigned)u << 16};
  return x.f;
}
__device__ inline void stv(float* p, float v) { *p = v; }
__device__ inline void stv(ushort* p, float v) { *p = f2b(v); }

__device__ inline void gld16(const void* g, void* l) {
  __builtin_amdgcn_global_load_lds(
      (const __attribute__((address_space(1))) void*)g,
      (__attribute__((address_space(3))) void*)l, 16, 0, 0);
}

// ---------------- elementwise / small kernels ----------------

__global__ void copy4_k(float4* __restrict__ dst, const float4* __restrict__ src) {
  long i = (long)blockIdx.x * blockDim.x + threadIdx.x;
  dst[i] = src[i];
}

__global__ void rope_tab_k(const int* __restrict__ pos, float* __restrict__ cosb,
                           float* __restrict__ sinb) {
  long bs = blockIdx.x;
  int d = threadIdx.x;
  int i = d & (DH / 2 - 1);
  float inv = expf(-(2.0f * (float)i / (float)DH) * logf(10000.0f));
  float ang = (float)pos[bs] * inv;
  cosb[bs * DH + d] = cosf(ang);
  sinb[bs * DH + d] = sinf(ang);
}

__global__ __launch_bounds__(256) void ada_k(const float* __restrict__ cond,
    const float* __restrict__ W, float* __restrict__ part, int D, int twoD) {
  __shared__ float lc[2 * 2048];
  int t = threadIdx.x;
  int j = blockIdx.x * 256 + t;
  int chunk = blockIdx.y;
  int cl = D / gridDim.y;
  int d0 = chunk * cl;
  for (int i = t; i < 2 * D; i += 256) lc[i] = cond[i];
  __syncthreads();
  float a0 = 0.f, a1 = 0.f;
  for (int d = d0; d < d0 + cl; ++d) {
    float wvv = W[(long)d * twoD + j];
    a0 = fmaf(lc[d], wvv, a0);
    a1 = fmaf(lc[D + d], wvv, a1);
  }
  part[((long)chunk * 2 + 0) * twoD + j] = a0;
  part[((long)chunk * 2 + 1) * twoD + j] = a1;
}

__global__ void ada_red_k(const float* __restrict__ part, float* __restrict__ sg,
                          int twoD, int nch) {
  int idx = blockIdx.x * 256 + threadIdx.x;
  int b = idx / twoD, j = idx - b * twoD;
  float s = 0.f;
  for (int c = 0; c < nch; ++c) s += part[((long)c * 2 + b) * twoD + j];
  sg[(long)b * twoD + j] = s;
}

template <typename OT>
__global__ __launch_bounds__(256) void rms_k(const float* __restrict__ x,
    const float* __restrict__ sg, OT* __restrict__ out, int D, int rowsPerB) {
  long row = blockIdx.x;
  int b = (int)(row / rowsPerB);
  const float* xr = x + row * (long)D;
  OT* po = out + row * (long)D;
  const float* sc = sg + (long)b * 2 * D;
  int t = threadIdx.x;
  float ss = 0.f;
  for (int i = t; i < D; i += 256) { float v = xr[i]; ss = fmaf(v, v, ss); }
  for (int o = 32; o; o >>= 1) ss += __shfl_xor(ss, o);
  __shared__ float wr[4];
  if ((t & 63) == 0) wr[t >> 6] = ss;
  __syncthreads();
  float rs = rsqrtf((wr[0] + wr[1] + wr[2] + wr[3]) / (float)D + 1e-6f);
  for (int i = t; i < D; i += 256) stv(po + i, xr[i] * rs * (1.f + sc[i]));
}

// x += (sum_c part[c*MN + idx]) * gate
__global__ void gared_k(float* __restrict__ x, const float* __restrict__ part,
                        const float* __restrict__ g, int D, int rowsPerB,
                        long MN, int ns) {
  long idx = (long)blockIdx.x * 256 + threadIdx.x;
  int d = (int)(idx % D);
  int b = (int)(idx / ((long)rowsPerB * D));
  float s = part[idx];
  for (int c = 1; c < ns; ++c) s += part[(long)c * MN + idx];
  x[idx] = fmaf(s, g[(long)b * 2 * D + d], x[idx]);
}

// fp32 [K][N] -> bf16 [N][K] transpose-convert
__global__ __launch_bounds__(256) void wconv_k(const float* __restrict__ in,
    ushort* __restrict__ out, int N, int K) {
  __shared__ float tile[64][65];
  int n0 = blockIdx.x << 6, k0 = blockIdx.y << 6;
  int t = threadIdx.x, r = t >> 4, c4 = (t & 15) << 2;
#pragma unroll
  for (int rr = 0; rr < 64; rr += 16) {
    float4 v = *(const float4*)(in + (long)(k0 + r + rr) * N + n0 + c4);
    tile[r + rr][c4 + 0] = v.x; tile[r + rr][c4 + 1] = v.y;
    tile[r + rr][c4 + 2] = v.z; tile[r + rr][c4 + 3] = v.w;
  }
  __syncthreads();
#pragma unroll
  for (int rr = 0; rr < 64; rr += 16) {
    int n = r + rr;
    ushort4 o;
    o.x = f2b(tile[c4 + 0][n]); o.y = f2b(tile[c4 + 1][n]);
    o.z = f2b(tile[c4 + 2][n]); o.w = f2b(tile[c4 + 3][n]);
    *(ushort4*)(out + (long)(n0 + n) * K + k0 + c4) = o;
  }
}

// fused qkv bf16 [B*Si][QKVN] -> RoPE -> qj/kj bf16 [B,NH,SEQ,DH]
__global__ __launch_bounds__(256) void rope_qk_k(const ushort* __restrict__ qkv,
    const float* __restrict__ cosb, const float* __restrict__ sinb,
    ushort* __restrict__ qj, ushort* __restrict__ kj, int Si, int ofs) {
  long bs = blockIdx.x;
  int b = (int)(bs / Si), s = (int)(bs % Si);
  int c = blockIdx.y * 256 + threadIdx.x;
  int h = c >> 8, hd = c & 255;
  long tin = bs * (long)QKVN;
  float q = b2f(qkv[tin + c]), k = b2f(qkv[tin + HH + c]);
  float qp = b2f(qkv[tin + (c ^ 128)]), kp = b2f(qkv[tin + HH + (c ^ 128)]);
  long sgi = ((long)b * SEQ + ofs + s) * DH + hd;
  float cv = cosb[sgi], sv = sinb[sgi];
  float qr = (hd < 128) ? -qp : qp, kr = (hd < 128) ? -kp : kp;
  long o = (((long)b * NH + h) * SEQ + ofs + s) * (long)DH + hd;
  qj[o] = f2b(fmaf(q, cv, qr * sv));
  kj[o] = f2b(fmaf(k, cv, kr * sv));
}

// v (cols [2*HH,3*HH) of qkv) [B*Si][QKVN] -> vjT bf16 [B,NH,DH,SEQ]
__global__ __launch_bounds__(256) void vtrans_k(const ushort* __restrict__ qkv,
    ushort* __restrict__ vjT, int Si, int ofs) {
  __shared__ ushort tile[64][80];
  int z = blockIdx.z, b = z >> 3, h = z & 7;
  int s0 = blockIdx.x << 6, d0 = blockIdx.y << 6;
  int t = threadIdx.x, r = t >> 3, c8 = (t & 7) << 3;
#pragma unroll
  for (int rr = 0; rr < 64; rr += 32) {
    const ushort* src = qkv + (long)(b * Si + s0 + r + rr) * QKVN + 2 * HH + h * DH + d0 + c8;
    *(uint4*)&tile[r + rr][c8] = *(const uint4*)src;
  }
  __syncthreads();
#pragma unroll
  for (int rr = 0; rr < 64; rr += 32) {
    int drow = r + rr;
    ushort o[8];
#pragma unroll
    for (int j = 0; j < 8; ++j) o[j] = tile[c8 + j][drow];
    *(uint4*)(vjT + ((long)(b * NH + h) * DH + d0 + drow) * SEQ + ofs + s0 + c8) =
        *(const uint4*)o;
  }
}

// softmax over fp32 scores row; writes bf16 probs in place (first half of row)
__global__ __launch_bounds__(256) void softmax_k(float* __restrict__ scores) {
  float* p = scores + (long)blockIdx.y * SEQ * SEQ + (long)blockIdx.x * SEQ;
  ushort* po = (ushort*)p;
  int t = threadIdx.x;
  float v[5];
  float mx = -3.4e38f;
#pragma unroll
  for (int i = 0; i < 5; ++i) { v[i] = p[t + i * 256] * 0.0625f; mx = fmaxf(mx, v[i]); }
  for (int o = 32; o; o >>= 1) mx = fmaxf(mx, __shfl_xor(mx, o));
  __shared__ float wr[4];
  if ((t & 63) == 0) wr[t >> 6] = mx;
  __syncthreads();
  mx = fmaxf(fmaxf(wr[0], wr[1]), fmaxf(wr[2], wr[3]));
  __syncthreads();
  float s = 0.f;
#pragma unroll
  for (int i = 0; i < 5; ++i) { v[i] = expf(v[i] - mx); s += v[i]; }
  for (int o = 32; o; o >>= 1) s += __shfl_xor(s, o);
  if ((t & 63) == 0) wr[t >> 6] = s;
  __syncthreads();
  float inv = 1.f / (wr[0] + wr[1] + wr[2] + wr[3]);
#pragma unroll
  for (int i = 0; i < 5; ++i) po[t + i * 256] = f2b(v[i] * inv);
}

// out[m][f] = gelu(in[m][f]) * in[m][F+f]
__global__ __launch_bounds__(256) void gelumul_k(const ushort* __restrict__ in,
    ushort* __restrict__ out, int F) {
  long v = (long)blockIdx.x * 256 + threadIdx.x;
  int fv = F >> 3;
  long m = v / fv; int f8 = (int)(v % fv) << 3;
  const ushort* gp = in + m * 2 * F + f8;
  uint4 gv = *(const uint4*)gp;
  uint4 uv = *(const uint4*)(gp + F);
  const ushort* gs = (const ushort*)&gv;
  const ushort* us = (const ushort*)&uv;
  ushort ov[8];
#pragma unroll
  for (int j = 0; j < 8; ++j) {
    float g = b2f(gs[j]);
    float ge = 0.5f * g * (1.f + tanhf(0.7978845608028654f * fmaf(0.044715f * g, g * g, g)));
    ov[j] = f2b(ge * b2f(us[j]));
  }
  *(uint4*)(out + m * F + f8) = *(const uint4*)ov;
}

// ---------------- bf16 MFMA GEMM, 128x128 (m97 structure) ----------------
template <int EPI>
__global__ __launch_bounds__(256) void bgemm_k(
    const ushort* __restrict__ A, const ushort* __restrict__ B,
    float* __restrict__ Cf, ushort* __restrict__ Cb, int K,
    int lda, int ldb, int ldc,
    long sA1, long sA2, long sB1, long sB2, long sC1, long sC2, int bdiv) {
  __shared__ ushort As[128 * 32];
  __shared__ ushort Bs[128 * 32];
  int t = threadIdx.x;
  int z = blockIdx.z, z1 = z / bdiv, z2 = z % bdiv;
  A += z1 * sA1 + z2 * sA2;
  B += z1 * sB1 + z2 * sB2;
  long cofs = z1 * sC1 + z2 * sC2;
  int m0 = blockIdx.y * 128, n0 = blockIdx.x * 128;
  int srow = t >> 2, scol = (t & 3) << 3;
  const ushort* gA0 = A + (long)(m0 + srow) * lda + scol;
  const ushort* gA1 = A + (long)(m0 + srow + 64) * lda + scol;
  const ushort* gB0 = B + (long)(n0 + srow) * ldb + scol;
  const ushort* gB1 = B + (long)(n0 + srow + 64) * ldb + scol;
  ushort* lA0 = &As[srow * 32 + scol];
  ushort* lA1 = &As[(srow + 64) * 32 + scol];
  ushort* lB0 = &Bs[srow * 32 + scol];
  ushort* lB1 = &Bs[(srow + 64) * 32 + scol];
  int lane = t & 63;
  int wm = ((t >> 6) & 1) << 6, wn = (t >> 7) << 6;
  int fr = lane & 15, fk = (lane >> 4) << 3;
  f32x4 acc[4][4] = {};
  for (int k0 = 0; k0 < K; k0 += 32) {
    if (k0) __syncthreads();
    gld16(gA0 + k0, lA0);
    gld16(gA1 + k0, lA1);
    gld16(gB0 + k0, lB0);
    gld16(gB1 + k0, lB1);
    __syncthreads();
    bf16x8 a[4], b[4];
#pragma unroll
    for (int m = 0; m < 4; ++m)
      a[m] = *(const bf16x8*)&As[(wm + m * 16 + fr) * 32 + fk];
#pragma unroll
    for (int n = 0; n < 4; ++n)
      b[n] = *(const bf16x8*)&Bs[(wn + n * 16 + fr) * 32 + fk];
#pragma unroll
    for (int m = 0; m < 4; ++m)
#pragma unroll
      for (int n = 0; n < 4; ++n)
        acc[m][n] = __builtin_amdgcn_mfma_f32_16x16x32_bf16(a[m], b[n], acc[m][n], 0, 0, 0);
  }
  int cr = (lane >> 4) << 2, cc = lane & 15;
#pragma unroll
  for (int m = 0; m < 4; ++m) {
    int row = m0 + wm + m * 16 + cr;
#pragma unroll
    for (int n = 0; n < 4; ++n) {
      int col = n0 + wn + n * 16 + cc;
#pragma unroll
      for (int r = 0; r < 4; ++r) {
        long idx = cofs + (long)(row + r) * ldc + col;
        if (EPI == 0) Cf[idx] = acc[m][n][r];
        else Cb[idx] = f2b(acc[m][n][r]);
      }
    }
  }
}

// ---------------- bf16 MFMA GEMM, 256x256, 8-phase (m201 template) ----------
// 512 threads = 8 waves (2M x 4N), per-wave 128x64 output, BK=64 (2 k-words).
// LDS: 2 K-tile buffers x {A,B} x [2 kw][256 rows][32] = 128 KiB.
// Per phase: {ds-read frags | stage 1 plane (2 gld_lds) | barrier | 16 MFMA |
// barrier}; counted vmcnt(2) only at phases 3 and 7 (buffer switch points).
// Slot swizzle: phys slot = logical ^ ((row>>1)&3), pre-swizzled global src.
// Requires K % 128 == 0, M % 256 == 0, N % 256 == 0.
template <int EPI>
__global__ __launch_bounds__(512, 2) void bgemm8_k(
    const ushort* __restrict__ A, const ushort* __restrict__ B,
    float* __restrict__ Cf, ushort* __restrict__ Cb, int K,
    int lda, int ldb, int ldc,
    long sA1, long sA2, long sB1, long sB2, long sC1, long sC2, int bdiv) {
  __shared__ ushort As[2][2][256 * 32];
  __shared__ ushort Bs[2][2][256 * 32];
  int t = threadIdx.x;
  int z = blockIdx.z, z1 = z / bdiv, z2 = z % bdiv;
  A += z1 * sA1 + z2 * sA2;
  B += z1 * sB1 + z2 * sB2;
  long cofs = z1 * sC1 + z2 * sC2;
  // m-major bijective XCD swizzle: co-resident blocks share B panels
  int gy = gridDim.y, nwg = gridDim.x * gy;
  int wg = blockIdx.y * gridDim.x + blockIdx.x;
  int q8 = nwg >> 3, r8 = nwg & 7;
  int xcd = wg & 7, wi = wg >> 3;
  int swz = (xcd < r8 ? xcd * (q8 + 1) : r8 * (q8 + 1) + (xcd - r8) * q8) + wi;
  int m0 = (swz % gy) << 8;
  int n0 = (swz / gy) << 8;

  int srow = t >> 2;
  int scol = ((t & 3) ^ ((srow >> 1) & 3)) << 3;  // pre-swizzled source col
  const ushort* ga = A + (long)(m0 + srow) * lda + scol;
  const ushort* gb = B + (long)(n0 + srow) * ldb + scol;
  long a128 = (long)128 * lda, b128 = (long)128 * ldb;

  int lane = t & 63, wid = t >> 6;
  int wm = wid >> 2, wn = wid & 3;
  int fr = lane & 15, sl = lane >> 4;

  int ao[2][4], bo[4];
#pragma unroll
  for (int mq = 0; mq < 2; ++mq)
#pragma unroll
    for (int mi = 0; mi < 4; ++mi) {
      int row = wm * 128 + mq * 64 + mi * 16 + fr;
      ao[mq][mi] = row * 32 + ((sl ^ ((row >> 1) & 3)) << 3);
    }
#pragma unroll
  for (int nf = 0; nf < 4; ++nf) {
    int row = wn * 64 + nf * 16 + fr;
    bo[nf] = row * 32 + ((sl ^ ((row >> 1) & 3)) << 3);
  }

  f32x4 acc[8][4] = {};
  int nkt = K >> 6;

#define STGA(kt, kw) { const ushort* s_ = ga + ((long)(kt) << 6) + ((kw) << 5); \
    gld16(s_, &As[(kt) & 1][kw][t * 8]);                                        \
    gld16(s_ + a128, &As[(kt) & 1][kw][4096 + t * 8]); }
#define STGB(kt, kw) { const ushort* s_ = gb + ((long)(kt) << 6) + ((kw) << 5); \
    gld16(s_, &Bs[(kt) & 1][kw][t * 8]);                                        \
    gld16(s_ + b128, &Bs[(kt) & 1][kw][4096 + t * 8]); }

  // prologue: K-tile 0 fully, K-tile 1 A-kw0; then wait + barrier
  STGA(0, 0); STGA(0, 1); STGB(0, 0); STGB(0, 1);
  if (nkt > 1) STGA(1, 0);
  asm volatile("s_waitcnt vmcnt(2)" ::: "memory");
  __builtin_amdgcn_s_barrier();
  __builtin_amdgcn_sched_barrier(0);

  bf16x8 a[4][2], b[4][2];
  for (int it = 0; it < nkt; it += 2) {
#pragma unroll
    for (int p = 0; p < 8; ++p) {
      const int buf = p >> 2;            // it is even
      const int q = p & 3, mq = q >> 1, nq = q & 1;
      if (q == 0) {
#pragma unroll
        for (int x = 0; x < 4; ++x) {
          a[x][0] = *(const bf16x8*)&As[buf][0][ao[0][x]];
          a[x][1] = *(const bf16x8*)&As[buf][1][ao[0][x]];
        }
#pragma unroll
        for (int nf = 0; nf < 4; ++nf) {
          b[nf][0] = *(const bf16x8*)&Bs[buf][0][bo[nf]];
          b[nf][1] = *(const bf16x8*)&Bs[buf][1][bo[nf]];
        }
      } else if (q == 2) {
#pragma unroll
        for (int x = 0; x < 4; ++x) {
          a[x][0] = *(const bf16x8*)&As[buf][0][ao[1][x]];
          a[x][1] = *(const bf16x8*)&As[buf][1][ao[1][x]];
        }
      }
      // rolling stage schedule (one plane per phase); vmcnt only at p3/p7
      if (p == 0) { STGA(it + 1, 1); }
      else if (p == 1) { STGB(it + 1, 0); }
      else if (p == 2) { STGB(it + 1, 1); }
      else if (p == 3) {
        if (it + 2 < nkt) { STGA(it + 2, 0);
          asm volatile("s_waitcnt vmcnt(2)" ::: "memory");
        } else asm volatile("s_waitcnt vmcnt(0)" ::: "memory");
      }
      else if (p == 4) { if (it + 2 < nkt) STGA(it + 2, 1); }
      else if (p == 5) { if (it + 2 < nkt) STGB(it + 2, 0); }
      else if (p == 6) { if (it + 2 < nkt) STGB(it + 2, 1); }
      else {  // p == 7
        if (it + 3 < nkt) { STGA(it + 3, 0);
          asm volatile("s_waitcnt vmcnt(2)" ::: "memory");
        } else asm volatile("s_waitcnt vmcnt(0)" ::: "memory");
      }
      __builtin_amdgcn_s_barrier();
      if (p == 3 || p == 7) __builtin_amdgcn_sched_barrier(0);
      __builtin_amdgcn_s_setprio(1);
#pragma unroll
      for (int mi = 0; mi < 4; ++mi)
#pragma unroll
        for (int ni = 0; ni < 2; ++ni)
#pragma unroll
          for (int kw = 0; kw < 2; ++kw)
            acc[mq * 4 + mi][nq * 2 + ni] = __builtin_amdgcn_mfma_f32_16x16x32_bf16(
                a[mi][kw], b[nq * 2 + ni][kw], acc[mq * 4 + mi][nq * 2 + ni], 0, 0, 0);
      __builtin_amdgcn_s_setprio(0);
      __builtin_amdgcn_s_barrier();
    }
  }
#undef STGA
#undef STGB

  int cr = sl << 2, cc = fr;
#pragma unroll
  for (int m = 0; m < 8; ++m) {
    int row = m0 + wm * 128 + m * 16 + cr;
#pragma unroll
    for (int n = 0; n < 4; ++n) {
      int col = n0 + wn * 64 + n * 16 + cc;
#pragma unroll
      for (int rr = 0; rr < 4; ++rr) {
        long idx = cofs + (long)(row + rr) * ldc + col;
        if (EPI == 0) Cf[idx] = acc[m][n][rr];
        else Cb[idx] = f2b(acc[m][n][rr]);
      }
    }
  }
}

}  // namespace

extern "C" void kernel_launch(void* const* d_in, const int* in_sizes, int n_in,
                              void* d_out, int out_size, void* d_ws, size_t ws_size,
                              hipStream_t stream) {
  (void)in_sizes; (void)n_in; (void)out_size;
  const float* emb_p = (const float*)d_in[0];
  const float* emb_e = (const float*)d_in[1];
  const float* cond[2] = {(const float*)d_in[2], (const float*)d_in[3]};
  const float* ada1[2] = {(const float*)d_in[4], (const float*)d_in[14]};
  const float* ada2[2] = {(const float*)d_in[5], (const float*)d_in[15]};
  const float* adaF[2] = {(const float*)d_in[6], (const float*)d_in[16]};
  const float* wq[2] = {(const float*)d_in[7], (const float*)d_in[17]};
  const float* wk[2] = {(const float*)d_in[8], (const float*)d_in[18]};
  const float* wv[2] = {(const float*)d_in[9], (const float*)d_in[19]};
  const float* wo[2] = {(const float*)d_in[10], (const float*)d_in[20]};
  const float* wg[2] = {(const float*)d_in[11], (const float*)d_in[21]};
  const float* wu[2] = {(const float*)d_in[12], (const float*)d_in[22]};
  const float* wd[2] = {(const float*)d_in[13], (const float*)d_in[23]};
  const int* pos = (const int*)d_in[24];

  const int Ds[2] = {DIMP, DIME};
  const int Fs[2] = {FFP, FFE};
  const int Sis[2] = {SEQP, SEQS};
  const int ofss[2] = {0, SEQP};

  char* base = (char*)d_ws;
  size_t off = 0;
  auto alF = [&](size_t n) { float* r = (float*)(base + off); off += (n * 4 + 255) & ~(size_t)255; return r; };
  auto alH = [&](size_t n) { ushort* r = (ushort*)(base + off); off += (n * 2 + 255) & ~(size_t)255; return r; };

  float* xs[2]; ushort* hb[2]; float* sg[2];
  xs[0] = alF((size_t)NB * SEQP * DIMP);
  xs[1] = alF((size_t)NB * SEQS * DIME);
  float* cosb = alF((size_t)NB * SEQ * DH);
  float* sinb = alF((size_t)NB * SEQ * DH);
  sg[0] = alF((size_t)NB * 2 * DIMP);
  sg[1] = alF((size_t)NB * 2 * DIME);
  float* part = alF((size_t)8 * 2 * 2 * DIMP);
  float* scores = alF((size_t)NB * NH * SEQ * SEQ);  // 105MB; also pbuf/ffb2/ffb
  hb[0] = alH((size_t)NB * SEQP * DIMP);
  hb[1] = alH((size_t)NB * SEQS * DIME);
  ushort* qkvt = alH((size_t)NB * SEQP * QKVN);
  ushort* qj = alH((size_t)NB * NH * SEQ * DH);
  ushort* kj = alH((size_t)NB * NH * SEQ * DH);
  ushort* vjT = alH((size_t)NB * NH * DH * SEQ);
  ushort* att2b = alH((size_t)NB * SEQ * HH);
  ushort* wT = alH((size_t)2 * FFP * DIMP);  // fused gate|up is the largest
  if (off > ws_size) return;  // fail loudly (output stays poisoned)

  float* pbuf = scores;                    // split-K partials (<= 67MB)
  ushort* ffb2 = (ushort*)scores;          // [M][2F] raw gate|up (<= 67MB)
  ushort* ffb = (ushort*)((char*)scores + (size_t)70 * 1024 * 1024);  // [M][F]

  copy4_k<<<(NB * SEQP * DIMP / 4) / 256, 256, 0, stream>>>((float4*)xs[0], (const float4*)emb_p);
  copy4_k<<<(NB * SEQS * DIME / 4) / 256, 256, 0, stream>>>((float4*)xs[1], (const float4*)emb_e);
  rope_tab_k<<<NB * SEQ, DH, 0, stream>>>(pos, cosb, sinb);

  for (int l = 0; l < NL; ++l) {
    for (int i = 0; i < 2; ++i) {
      int D = Ds[i], Si = Sis[i], M = NB * Si;
      const float* a1 = ada1[i] + (size_t)l * D * 2 * D;
      ada_k<<<dim3(2 * D / 256, 8), 256, 0, stream>>>(cond[i], a1, part, D, 2 * D);
      ada_red_k<<<4 * D / 256, 256, 0, stream>>>(part, sg[i], 2 * D, 8);
      rms_k<ushort><<<M, 256, 0, stream>>>(xs[i], sg[i], hb[i], D, Si);
      const float* W3[3] = {wq[i] + (size_t)l * D * HH, wk[i] + (size_t)l * D * HH,
                            wv[i] + (size_t)l * D * HH};
      for (int j = 0; j < 3; ++j)
        wconv_k<<<dim3(HH / 64, D / 64), 256, 0, stream>>>(W3[j], wT + (size_t)j * HH * D, HH, D);
      if (i == 0)
        bgemm8_k<1><<<dim3(QKVN / 256, M / 256, 1), 512, 0, stream>>>(
            hb[i], wT, nullptr, qkvt, D, D, D, QKVN, 0, 0, 0, 0, 0, 0, 1);
      else
        bgemm_k<1><<<dim3(QKVN / 128, M / 128, 1), 256, 0, stream>>>(
            hb[i], wT, nullptr, qkvt, D, D, D, QKVN, 0, 0, 0, 0, 0, 0, 1);
      rope_qk_k<<<dim3(M, HH / 256), 256, 0, stream>>>(qkvt, cosb, sinb, qj, kj, Si, ofss[i]);
      vtrans_k<<<dim3(Si / 64, DH / 64, NB * NH), 256, 0, stream>>>(qkvt, vjT, Si, ofss[i]);
    }
    // joint attention
    bgemm8_k<0><<<dim3(SEQ / 256, SEQ / 256, NB * NH), 512, 0, stream>>>(
        qj, kj, scores, nullptr, DH, DH, DH, SEQ,
        (long)SEQ * DH, 0, (long)SEQ * DH, 0, (long)SEQ * SEQ, 0, 1);
    softmax_k<<<dim3(SEQ, NB * NH), 256, 0, stream>>>(scores);
    bgemm_k<1><<<dim3(DH / 128, SEQ / 128, NB * NH), 256, 0, stream>>>(
        (const ushort*)scores, vjT, nullptr, att2b, SEQ, 2 * SEQ, SEQ, HH,
        (long)2 * NH * SEQ * SEQ, (long)2 * SEQ * SEQ,
        (long)NH * DH * SEQ, (long)DH * SEQ,
        (long)SEQ * HH, (long)DH, NH);
    for (int i = 0; i < 2; ++i) {
      int D = Ds[i], F = Fs[i], Si = Sis[i], M = NB * Si;
      // WO, split-K x4 (Kc = 512) into pbuf, then fused reduce+gated-add
      wconv_k<<<dim3(D / 64, HH / 64), 256, 0, stream>>>(wo[i] + (size_t)l * HH * D, wT, D, HH);
      if (i == 0)
        bgemm8_k<0><<<dim3(D / 256, Si / 256, NB * 4), 512, 0, stream>>>(
            att2b, wT, pbuf, nullptr, 512, HH, HH, D,
            (long)SEQ * HH, 512, 0, 512, (long)Si * D, (long)M * D, 4);
      else
        bgemm_k<0><<<dim3(D / 128, Si / 128, NB * 4), 256, 0, stream>>>(
            att2b + (size_t)ofss[i] * HH, wT, pbuf, nullptr, 512, HH, HH, D,
            (long)SEQ * HH, 512, 0, 512, (long)Si * D, (long)M * D, 4);
      gared_k<<<M * D / 256, 256, 0, stream>>>(xs[i], pbuf, sg[i] + D, D, Si,
                                               (long)M * D, 4);
      const float* a2 = ada2[i] + (size_t)l * D * 2 * D;
      ada_k<<<dim3(2 * D / 256, 8), 256, 0, stream>>>(cond[i], a2, part, D, 2 * D);
      ada_red_k<<<4 * D / 256, 256, 0, stream>>>(part, sg[i], 2 * D, 8);
      rms_k<ushort><<<M, 256, 0, stream>>>(xs[i], sg[i], hb[i], D, Si);
      // fused gate|up -> ffb2 [M][2F], then gelu*up -> ffb [M][F]
      wconv_k<<<dim3(F / 64, D / 64), 256, 0, stream>>>(wg[i] + (size_t)l * D * F, wT, F, D);
      wconv_k<<<dim3(F / 64, D / 64), 256, 0, stream>>>(wu[i] + (size_t)l * D * F,
                                                        wT + (size_t)F * D, F, D);
      if (i == 0)
        bgemm8_k<1><<<dim3(2 * F / 256, M / 256, 1), 512, 0, stream>>>(
            hb[i], wT, nullptr, ffb2, D, D, D, 2 * F, 0, 0, 0, 0, 0, 0, 1);
      else
        bgemm_k<1><<<dim3(2 * F / 128, M / 128, 1), 256, 0, stream>>>(
            hb[i], wT, nullptr, ffb2, D, D, D, 2 * F, 0, 0, 0, 0, 0, 0, 1);
      gelumul_k<<<(long)M * F / 8 / 256, 256, 0, stream>>>(ffb2, ffb, F);
      // down, split-K into pbuf, fused reduce+gated-add
      wconv_k<<<dim3(D / 64, F / 64), 256, 0, stream>>>(wd[i] + (size_t)l * F * D, wT, D, F);
      if (i == 0)
        bgemm8_k<0><<<dim3(D / 256, M / 256, 4), 512, 0, stream>>>(
            ffb, wT, pbuf, nullptr, F / 4, F, F, D,
            0, F / 4, 0, F / 4, 0, (long)M * D, 4);
      else
        bgemm_k<0><<<dim3(D / 128, M / 128, 8), 256, 0, stream>>>(
            ffb, wT, pbuf, nullptr, F / 8, F, F, D,
            0, F / 8, 0, F / 8, 0, (long)M * D, 8);
      gared_k<<<M * D / 256, 256, 0, stream>>>(xs[i], pbuf, sg[i] + D, D, Si,
                                               (long)M * D, i == 0 ? 4 : 8);
    }
  }
  float* outp = (float*)d_out;
  for (int i = 0; i < 2; ++i) {
    int D = Ds[i], Si = Sis[i];
    ada_k<<<dim3(2 * D / 256, 8), 256, 0, stream>>>(cond[i], adaF[i], part, D, 2 * D);
    ada_red_k<<<4 * D / 256, 256, 0, stream>>>(part, sg[i], 2 * D, 8);
    rms_k<float><<<NB * Si, 256, 0, stream>>>(xs[i], sg[i], outp, D, Si);
    outp += (size_t)NB * Si * D;
  }
}